// Round 3
// baseline (878.792 us; speedup 1.0000x reference)
//
#include <hip/hip_runtime.h>
#include <hip/hip_bf16.h>

using bf16 = __hip_bfloat16;
typedef __bf16 bf16x8 __attribute__((ext_vector_type(8)));
typedef __bf16 bf16x4 __attribute__((ext_vector_type(4)));
typedef float f32x4 __attribute__((ext_vector_type(4)));

#define BM 128
#define BN 128
#define BK 64

// ---------------------------------------------------------------------------
// Tiled MFMA GEMM: C[M,N] = act( A[M,K] @ B[N,K]^T + bias ), bf16 operands.
// A and B each split into two K-segments (dense weight | rank-128 delta
// factor) so the low-rank delta is a K-concatenation, not a second pass.
// Output: fp32 to Cf if non-null, else bf16 to C. bias is fp32.
// gscale (fp32, [16,128]) multiplies by gscale[(row>>9)*128 + col] (N==128).
// Requires: M%128==0, N%128==0, K0%64==0, K1%64==0. Block=256 (4 waves 2x2).
// ---------------------------------------------------------------------------
__global__ __launch_bounds__(256)
void gemm_bt(const bf16* __restrict__ A0, int lda0, int K0,
             const bf16* __restrict__ A1, int lda1, int K1,
             const bf16* __restrict__ B0, int ldb0,
             const bf16* __restrict__ B1, int ldb1,
             const float* __restrict__ bias,
             const float* __restrict__ gscale,
             int relu,
             bf16* __restrict__ C, float* __restrict__ Cf, int ldc)
{
    __shared__ bf16 sA[BM * BK];
    __shared__ bf16 sB[BN * BK];

    const int t = threadIdx.x;
    const int w = t >> 6;          // wave 0..3
    const int l = t & 63;          // lane
    const int wm = w >> 1;         // wave row (0..1)
    const int wn = w & 1;          // wave col (0..1)
    const int r = l & 15;          // MFMA row/col-in-frag
    const int q = l >> 4;          // quad 0..3
    const int rowA0 = blockIdx.x * BM;
    const int rowB0 = blockIdx.y * BN;

    f32x4 acc[4][4];
#pragma unroll
    for (int i = 0; i < 4; ++i)
#pragma unroll
        for (int j = 0; j < 4; ++j)
            acc[i][j] = (f32x4){0.f, 0.f, 0.f, 0.f};

    const int nK = (K0 + K1) >> 6;
    for (int kt = 0; kt < nK; ++kt) {
        const int k0 = kt << 6;
        const bf16 *Ap, *Bp;
        int la, lb, ks;
        if (k0 < K0) { Ap = A0; la = lda0; Bp = B0; lb = ldb0; ks = k0; }
        else         { Ap = A1; la = lda1; Bp = B1; lb = ldb1; ks = k0 - K0; }

        // load 4 A-chunks + 4 B-chunks (16B each) into registers
        uint4 va[4], vb[4];
#pragma unroll
        for (int it = 0; it < 4; ++it) {
            const int L   = it * 256 + t;   // 16B chunk id, 0..1023
            const int row = L >> 3;
            const int cb  = L & 7;
            va[it] = *(const uint4*)(Ap + (size_t)(rowA0 + row) * la + ks + cb * 8);
            vb[it] = *(const uint4*)(Bp + (size_t)(rowB0 + row) * lb + ks + cb * 8);
        }

        __syncthreads();  // previous tile's compute done before LDS overwrite
#pragma unroll
        for (int it = 0; it < 4; ++it) {
            const int L = it * 256 + t;
            *(uint4*)&sA[(size_t)L * 8] = va[it];
            *(uint4*)&sB[(size_t)L * 8] = vb[it];
        }
        __syncthreads();

#pragma unroll
        for (int kk = 0; kk < 2; ++kk) {
            bf16x8 aF[4], bF[4];
#pragma unroll
            for (int i = 0; i < 4; ++i)
                aF[i] = *(const bf16x8*)&sA[(wm * 64 + i * 16 + r) * BK + kk * 32 + q * 8];
#pragma unroll
            for (int j = 0; j < 4; ++j)
                bF[j] = *(const bf16x8*)&sB[(wn * 64 + j * 16 + r) * BK + kk * 32 + q * 8];
#pragma unroll
            for (int i = 0; i < 4; ++i)
#pragma unroll
                for (int j = 0; j < 4; ++j)
                    acc[i][j] = __builtin_amdgcn_mfma_f32_16x16x32_bf16(
                        aF[i], bF[j], acc[i][j], 0, 0, 0);
        }
    }

    // epilogue: C/D layout col = lane&15, row = quad*4 + reg  (m89/m91 verified)
#pragma unroll
    for (int i = 0; i < 4; ++i) {
#pragma unroll
        for (int j = 0; j < 4; ++j) {
#pragma unroll
            for (int rr = 0; rr < 4; ++rr) {
                const int row = rowA0 + wm * 64 + i * 16 + q * 4 + rr;
                const int col = rowB0 + wn * 64 + j * 16 + r;
                float v = acc[i][j][rr];
                if (bias)   v += bias[col];
                if (gscale) v *= gscale[(row >> 9) * 128 + col];
                if (relu)   v = v > 0.f ? v : 0.f;
                if (Cf) Cf[(size_t)row * ldc + col] = v;
                else    C[(size_t)row * ldc + col] = __float2bfloat16(v);
            }
        }
    }
}

// ---------------------------------------------------------------------------
// Prep kernels (fp32 inputs -> bf16 working copies)
// ---------------------------------------------------------------------------
__global__ void cvt_kernel(const float* __restrict__ src, bf16* __restrict__ dst, int n4)
{
    const int i = blockIdx.x * 256 + threadIdx.x;
    if (i < n4) {
        const float4 v = ((const float4*)src)[i];
        ((bf16x4*)dst)[i] = (bf16x4){(__bf16)v.x, (__bf16)v.y, (__bf16)v.z, (__bf16)v.w};
    }
}

// merged biases: b + 0.2 * sum_e TB[e]
__global__ void prep_b_kernel(const float* __restrict__ b1, const float* __restrict__ TB1,
                              const float* __restrict__ b2, const float* __restrict__ TB2,
                              float* __restrict__ b1m, float* __restrict__ b2m)
{
    const int i = blockIdx.x * 256 + threadIdx.x;
    if (i < 3072) {
        float s = 0.f;
        for (int e = 0; e < 8; ++e) s += TB1[e * 3072 + i];
        b1m[i] = b1[i] + 0.2f * s;
    } else if (i < 3840) {
        const int j = i - 3072;
        float s = 0.f;
        for (int e = 0; e < 8; ++e) s += TB2[e * 768 + j];
        b2m[j] = b2[j] + 0.2f * s;
    }
}

// U1 fp32 [128(ek),3072(f)] -> U1T bf16 [3072,128]; U2 [128,768] -> U2T [768,128]
__global__ void transpose_kernel(const float* __restrict__ U1, const float* __restrict__ U2,
                                 bf16* __restrict__ U1T, bf16* __restrict__ U2T)
{
    const int i = blockIdx.x * 256 + threadIdx.x;
    if (i < 3072 * 128) {
        const int f = i >> 7, ek = i & 127;
        U1T[i] = __float2bfloat16(U1[ek * 3072 + f]);
    }
    if (i < 768 * 128) {
        const int h = i >> 7, ek = i & 127;
        U2T[i] = __float2bfloat16(U2[ek * 768 + h]);
    }
}

// gw[b, ek] = mean_s g2[b, s, ek]
__global__ void mean_g2_kernel(const bf16* __restrict__ g2, float* __restrict__ gw)
{
    const int b = blockIdx.x;      // 0..15
    const int c = threadIdx.x;     // 0..127
    float s = 0.f;
    for (int si = 0; si < 512; ++si)
        s += __bfloat162float(g2[(size_t)(b * 512 + si) * 128 + c]);
    gw[b * 128 + c] = s * (1.0f / 512.0f);
}

// ---------------------------------------------------------------------------
extern "C" void kernel_launch(void* const* d_in, const int* in_sizes, int n_in,
                              void* d_out, int out_size, void* d_ws, size_t ws_size,
                              hipStream_t stream)
{
    // ALL inputs are fp32 per the reference (jnp.float32 everywhere).
    const float* x       = (const float*)d_in[0];   // [8192, 768]
    const float* gate_w1 = (const float*)d_in[1];   // [256, 768]
    const float* gate_b1 = (const float*)d_in[2];   // [256]
    const float* gate_w2 = (const float*)d_in[3];   // [128, 256]
    const float* gate_b2 = (const float*)d_in[4];   // [128]
    const float* W1      = (const float*)d_in[5];   // [3072, 768]
    const float* b1      = (const float*)d_in[6];   // [3072]
    const float* W2      = (const float*)d_in[7];   // [768, 3072]
    const float* b2      = (const float*)d_in[8];   // [768]
    const float* U1      = (const float*)d_in[9];   // [128, 3072]
    const float* SVH1    = (const float*)d_in[10];  // [128, 768]
    const float* U2      = (const float*)d_in[11];  // [128, 768]
    const float* SVH2    = (const float*)d_in[12];  // [128, 3072]
    const float* TB1     = (const float*)d_in[13];  // [8, 3072]
    const float* TB2     = (const float*)d_in[14];  // [8, 768]
    float* out = (float*)d_out;                     // [8192, 768] fp32

    // workspace carve-up (~86 MB)
    char* p = (char*)d_ws;
    auto alloc = [&](size_t bytes) {
        char* q = p;
        p += (bytes + 255) & ~(size_t)255;
        return q;
    };
    bf16* hbuf  = (bf16*)alloc((size_t)8192 * 3072 * 2);  // fc1 output h (relu'd)
    bf16* xb    = (bf16*)alloc((size_t)8192 * 768 * 2);   // x in bf16
    bf16* gbuf  = (bf16*)alloc((size_t)8192 * 256 * 2);   // router hidden
    bf16* g2buf = (bf16*)alloc((size_t)8192 * 128 * 2);   // router logits
    bf16* t1buf = (bf16*)alloc((size_t)8192 * 128 * 2);   // (x.SVH1^T)*gw
    bf16* t2buf = (bf16*)alloc((size_t)8192 * 128 * 2);   // (h.SVH2^T)*gw
    bf16* W1b   = (bf16*)alloc((size_t)3072 * 768 * 2);
    bf16* W2b   = (bf16*)alloc((size_t)768 * 3072 * 2);
    bf16* gw1b  = (bf16*)alloc((size_t)256 * 768 * 2);
    bf16* gw2b  = (bf16*)alloc((size_t)128 * 256 * 2);
    bf16* svh1b = (bf16*)alloc((size_t)128 * 768 * 2);
    bf16* svh2b = (bf16*)alloc((size_t)128 * 3072 * 2);
    bf16* U1T   = (bf16*)alloc((size_t)3072 * 128 * 2);
    bf16* U2T   = (bf16*)alloc((size_t)768 * 128 * 2);
    float* gw   = (float*)alloc(2048 * 4);                // [16, 128]
    float* b1m  = (float*)alloc(3072 * 4);
    float* b2m  = (float*)alloc(768 * 4);

    const dim3 blk(256);

    // fp32 -> bf16 working copies
    cvt_kernel<<<6144, blk, 0, stream>>>(x, xb, 1572864);
    cvt_kernel<<<2304, blk, 0, stream>>>(W1, W1b, 589824);
    cvt_kernel<<<2304, blk, 0, stream>>>(W2, W2b, 589824);
    cvt_kernel<<<192,  blk, 0, stream>>>(gate_w1, gw1b, 49152);
    cvt_kernel<<<32,   blk, 0, stream>>>(gate_w2, gw2b, 8192);
    cvt_kernel<<<96,   blk, 0, stream>>>(SVH1, svh1b, 24576);
    cvt_kernel<<<384,  blk, 0, stream>>>(SVH2, svh2b, 98304);
    transpose_kernel<<<1536, blk, 0, stream>>>(U1, U2, U1T, U2T);
    prep_b_kernel<<<15, blk, 0, stream>>>(b1, TB1, b2, TB2, b1m, b2m);

    // router: g = relu(x @ gate_w1^T + gate_b1)    [8192, 256]
    gemm_bt<<<dim3(64, 2), blk, 0, stream>>>(xb, 768, 768, nullptr, 0, 0,
                                             gw1b, 768, nullptr, 0,
                                             gate_b1, nullptr, 1, gbuf, nullptr, 256);
    // g2 = g @ gate_w2^T + gate_b2                 [8192, 128]
    gemm_bt<<<dim3(64, 1), blk, 0, stream>>>(gbuf, 256, 256, nullptr, 0, 0,
                                             gw2b, 256, nullptr, 0,
                                             gate_b2, nullptr, 0, g2buf, nullptr, 128);
    // gw = mean_s(g2)                              [16, 128]
    mean_g2_kernel<<<16, 128, 0, stream>>>(g2buf, gw);

    // t1 = (x @ SVH1^T) * gw                       [8192, 128]
    gemm_bt<<<dim3(64, 1), blk, 0, stream>>>(xb, 768, 768, nullptr, 0, 0,
                                             svh1b, 768, nullptr, 0,
                                             nullptr, gw, 0, t1buf, nullptr, 128);
    // h = relu([x|t1] @ [W1|U1T]^T + b1m)          [8192, 3072]
    gemm_bt<<<dim3(64, 24), blk, 0, stream>>>(xb, 768, 768, t1buf, 128, 128,
                                              W1b, 768, U1T, 128,
                                              b1m, nullptr, 1, hbuf, nullptr, 3072);
    // t2 = (h @ SVH2^T) * gw                       [8192, 128]
    gemm_bt<<<dim3(64, 1), blk, 0, stream>>>(hbuf, 3072, 3072, nullptr, 0, 0,
                                             svh2b, 3072, nullptr, 0,
                                             nullptr, gw, 0, t2buf, nullptr, 128);
    // out = [h|t2] @ [W2|U2T]^T + b2m  (fp32 out)  [8192, 768]
    gemm_bt<<<dim3(64, 6), blk, 0, stream>>>(hbuf, 3072, 3072, t2buf, 128, 128,
                                             W2b, 3072, U2T, 128,
                                             b2m, nullptr, 0, nullptr, out, 768);
}

// Round 4
// 384.208 us; speedup vs baseline: 2.2873x; 2.2873x over previous
//
#include <hip/hip_runtime.h>
#include <hip/hip_bf16.h>

using bf16 = __hip_bfloat16;
typedef __bf16 bf16x8 __attribute__((ext_vector_type(8)));
typedef __bf16 bf16x4 __attribute__((ext_vector_type(4)));
typedef float f32x4 __attribute__((ext_vector_type(4)));

#define BM 128
#define BN 128
#define BK 64

// ---------------------------------------------------------------------------
// Staging helper: one 64-element K-slice (BMxBK tile) via global_load_lds,
// 16B per lane, wave-uniform LDS base (m97 pattern, 874 TF verified lineage).
// ---------------------------------------------------------------------------
__device__ __forceinline__ void stage16(const bf16* gsrc, bf16* lds_base)
{
    __builtin_amdgcn_global_load_lds(
        (__attribute__((address_space(1))) void*)(void*)gsrc,
        (__attribute__((address_space(3))) void*)(void*)lds_base,
        16, 0, 0);
}

// ---------------------------------------------------------------------------
// Tiled MFMA GEMM: C[M,N] = act( A[M,K] @ B[N,K]^T + bias ), bf16 operands.
// A and B each split into two K-segments (dense weight | rank-128 delta
// factor) so the low-rank delta is a K-concatenation, not a second pass.
// Output: fp32 to Cf if non-null, else bf16 to C. bias fp32.
// gscale (fp32 [16,128]) multiplies by gscale[(row>>9)*128 + col].
// Requires M%128==0, N%128==0, K0%64==0, K1%64==0. Block=256 (4 waves 2x2).
// ---------------------------------------------------------------------------
__global__ __launch_bounds__(256)
void gemm_bt(const bf16* __restrict__ A0, int lda0, int K0,
             const bf16* __restrict__ A1, int lda1, int K1,
             const bf16* __restrict__ B0, int ldb0,
             const bf16* __restrict__ B1, int ldb1,
             const float* __restrict__ bias,
             const float* __restrict__ gscale,
             int relu,
             bf16* __restrict__ C, float* __restrict__ Cf, int ldc)
{
    __shared__ bf16 sA[BM * BK];
    __shared__ bf16 sB[BN * BK];

    const int t = threadIdx.x;
    const int w = t >> 6;          // wave 0..3
    const int l = t & 63;          // lane
    const int wm = w >> 1;         // wave row (0..1)
    const int wn = w & 1;          // wave col (0..1)
    const int r = l & 15;          // MFMA row/col-in-frag
    const int q = l >> 4;          // quad 0..3
    const int rowA0 = blockIdx.x * BM;
    const int rowB0 = blockIdx.y * BN;

    f32x4 acc[4][4];
#pragma unroll
    for (int i = 0; i < 4; ++i)
#pragma unroll
        for (int j = 0; j < 4; ++j)
            acc[i][j] = (f32x4){0.f, 0.f, 0.f, 0.f};

    const int nK = (K0 + K1) >> 6;
    for (int kt = 0; kt < nK; ++kt) {
        const int k0 = kt << 6;
        const bf16 *Ap, *Bp;
        int la, lb, ks;
        if (k0 < K0) { Ap = A0; la = lda0; Bp = B0; lb = ldb0; ks = k0; }
        else         { Ap = A1; la = lda1; Bp = B1; lb = ldb1; ks = k0 - K0; }

        __syncthreads();  // previous tile's compute done before LDS overwrite
#pragma unroll
        for (int it = 0; it < 4; ++it) {
            const int L   = it * 256 + t;   // 16B chunk id, 0..1023
            const int row = L >> 3;
            const int cb  = L & 7;
            stage16(Ap + (size_t)(rowA0 + row) * la + ks + cb * 8,
                    sA + (size_t)(it * 256 + (w << 6)) * 8);
            stage16(Bp + (size_t)(rowB0 + row) * lb + ks + cb * 8,
                    sB + (size_t)(it * 256 + (w << 6)) * 8);
        }
        __syncthreads();  // compiler drains vmcnt(0): tiles complete in LDS

#pragma unroll
        for (int kk = 0; kk < 2; ++kk) {
            bf16x8 aF[4], bF[4];
#pragma unroll
            for (int i = 0; i < 4; ++i)
                aF[i] = *(const bf16x8*)&sA[(wm * 64 + i * 16 + r) * BK + kk * 32 + q * 8];
#pragma unroll
            for (int j = 0; j < 4; ++j)
                bF[j] = *(const bf16x8*)&sB[(wn * 64 + j * 16 + r) * BK + kk * 32 + q * 8];
#pragma unroll
            for (int i = 0; i < 4; ++i)
#pragma unroll
                for (int j = 0; j < 4; ++j)
                    acc[i][j] = __builtin_amdgcn_mfma_f32_16x16x32_bf16(
                        aF[i], bF[j], acc[i][j], 0, 0, 0);
        }
    }

    // epilogue: C/D layout col = lane&15, row = quad*4 + reg  (m89/m91 verified)
#pragma unroll
    for (int i = 0; i < 4; ++i) {
#pragma unroll
        for (int j = 0; j < 4; ++j) {
#pragma unroll
            for (int rr = 0; rr < 4; ++rr) {
                const int row = rowA0 + wm * 64 + i * 16 + q * 4 + rr;
                const int col = rowB0 + wn * 64 + j * 16 + r;
                float v = acc[i][j][rr];
                if (bias)   v += bias[col];
                if (gscale) v *= gscale[(row >> 9) * 128 + col];
                if (relu)   v = v > 0.f ? v : 0.f;
                if (Cf) Cf[(size_t)row * ldc + col] = v;
                else    C[(size_t)row * ldc + col] = __float2bfloat16(v);
            }
        }
    }
}

// ---------------------------------------------------------------------------
// Split-K GEMM for thin-N products: Cpart[z][M][N] = A @ B^T over this z's
// K-range. grid (M/128, N/128, S); each z handles ktiles_per 64-wide tiles.
// Deterministic (separate partial buffers, no atomics); bias/scale/act are
// applied by combine_kernel after the sum.
// ---------------------------------------------------------------------------
__global__ __launch_bounds__(256)
void gemm_splitk(const bf16* __restrict__ A, int lda,
                 const bf16* __restrict__ B, int ldb,
                 int ktiles_per, float* __restrict__ Cpart)
{
    __shared__ bf16 sA[BM * BK];
    __shared__ bf16 sB[BN * BK];

    const int t = threadIdx.x;
    const int w = t >> 6;
    const int l = t & 63;
    const int wm = w >> 1;
    const int wn = w & 1;
    const int r = l & 15;
    const int q = l >> 4;
    const int rowA0 = blockIdx.x * BM;
    const int rowB0 = blockIdx.y * BN;
    const int M = gridDim.x * BM;
    const int N = gridDim.y * BN;
    const int ksbase = blockIdx.z * ktiles_per * BK;

    f32x4 acc[4][4];
#pragma unroll
    for (int i = 0; i < 4; ++i)
#pragma unroll
        for (int j = 0; j < 4; ++j)
            acc[i][j] = (f32x4){0.f, 0.f, 0.f, 0.f};

    for (int kt = 0; kt < ktiles_per; ++kt) {
        const int ks = ksbase + kt * BK;

        __syncthreads();
#pragma unroll
        for (int it = 0; it < 4; ++it) {
            const int L   = it * 256 + t;
            const int row = L >> 3;
            const int cb  = L & 7;
            stage16(A + (size_t)(rowA0 + row) * lda + ks + cb * 8,
                    sA + (size_t)(it * 256 + (w << 6)) * 8);
            stage16(B + (size_t)(rowB0 + row) * ldb + ks + cb * 8,
                    sB + (size_t)(it * 256 + (w << 6)) * 8);
        }
        __syncthreads();

#pragma unroll
        for (int kk = 0; kk < 2; ++kk) {
            bf16x8 aF[4], bF[4];
#pragma unroll
            for (int i = 0; i < 4; ++i)
                aF[i] = *(const bf16x8*)&sA[(wm * 64 + i * 16 + r) * BK + kk * 32 + q * 8];
#pragma unroll
            for (int j = 0; j < 4; ++j)
                bF[j] = *(const bf16x8*)&sB[(wn * 64 + j * 16 + r) * BK + kk * 32 + q * 8];
#pragma unroll
            for (int i = 0; i < 4; ++i)
#pragma unroll
                for (int j = 0; j < 4; ++j)
                    acc[i][j] = __builtin_amdgcn_mfma_f32_16x16x32_bf16(
                        aF[i], bF[j], acc[i][j], 0, 0, 0);
        }
    }

    float* Cz = Cpart + (size_t)blockIdx.z * M * N;
#pragma unroll
    for (int i = 0; i < 4; ++i)
#pragma unroll
        for (int j = 0; j < 4; ++j)
#pragma unroll
            for (int rr = 0; rr < 4; ++rr) {
                const int row = rowA0 + wm * 64 + i * 16 + q * 4 + rr;
                const int col = rowB0 + wn * 64 + j * 16 + r;
                Cz[(size_t)row * N + col] = acc[i][j][rr];
            }
}

// sum S partials + bias + gscale + relu -> bf16. N must be power of two.
__global__ void combine_kernel(const float* __restrict__ parts, int S,
                               int MN, int nshift,
                               const float* __restrict__ bias,
                               const float* __restrict__ gscale,
                               int relu, bf16* __restrict__ outb)
{
    const int i = blockIdx.x * 256 + threadIdx.x;
    if (i >= MN) return;
    const int col = i & ((1 << nshift) - 1);
    const int row = i >> nshift;
    float s = 0.f;
    for (int z = 0; z < S; ++z) s += parts[(size_t)z * MN + i];
    if (bias)   s += bias[col];
    if (gscale) s *= gscale[(row >> 9) * 128 + col];
    if (relu)   s = s > 0.f ? s : 0.f;
    outb[i] = __float2bfloat16(s);
}

// ---------------------------------------------------------------------------
// Prep kernels (fp32 inputs -> bf16 working copies)
// ---------------------------------------------------------------------------
__global__ void cvt_kernel(const float* __restrict__ src, bf16* __restrict__ dst, int n4)
{
    const int i = blockIdx.x * 256 + threadIdx.x;
    if (i < n4) {
        const float4 v = ((const float4*)src)[i];
        ((bf16x4*)dst)[i] = (bf16x4){(__bf16)v.x, (__bf16)v.y, (__bf16)v.z, (__bf16)v.w};
    }
}

__global__ void prep_b_kernel(const float* __restrict__ b1, const float* __restrict__ TB1,
                              const float* __restrict__ b2, const float* __restrict__ TB2,
                              float* __restrict__ b1m, float* __restrict__ b2m)
{
    const int i = blockIdx.x * 256 + threadIdx.x;
    if (i < 3072) {
        float s = 0.f;
        for (int e = 0; e < 8; ++e) s += TB1[e * 3072 + i];
        b1m[i] = b1[i] + 0.2f * s;
    } else if (i < 3840) {
        const int j = i - 3072;
        float s = 0.f;
        for (int e = 0; e < 8; ++e) s += TB2[e * 768 + j];
        b2m[j] = b2[j] + 0.2f * s;
    }
}

__global__ void transpose_kernel(const float* __restrict__ U1, const float* __restrict__ U2,
                                 bf16* __restrict__ U1T, bf16* __restrict__ U2T)
{
    const int i = blockIdx.x * 256 + threadIdx.x;
    if (i < 3072 * 128) {
        const int f = i >> 7, ek = i & 127;
        U1T[i] = __float2bfloat16(U1[ek * 3072 + f]);
    }
    if (i < 768 * 128) {
        const int h = i >> 7, ek = i & 127;
        U2T[i] = __float2bfloat16(U2[ek * 768 + h]);
    }
}

__global__ void mean_g2_kernel(const bf16* __restrict__ g2, float* __restrict__ gw)
{
    const int b = blockIdx.x;      // 0..15
    const int c = threadIdx.x;     // 0..127
    float s = 0.f;
    for (int si = 0; si < 512; ++si)
        s += __bfloat162float(g2[(size_t)(b * 512 + si) * 128 + c]);
    gw[b * 128 + c] = s * (1.0f / 512.0f);
}

// ---------------------------------------------------------------------------
extern "C" void kernel_launch(void* const* d_in, const int* in_sizes, int n_in,
                              void* d_out, int out_size, void* d_ws, size_t ws_size,
                              hipStream_t stream)
{
    const float* x       = (const float*)d_in[0];   // [8192, 768]
    const float* gate_w1 = (const float*)d_in[1];   // [256, 768]
    const float* gate_b1 = (const float*)d_in[2];   // [256]
    const float* gate_w2 = (const float*)d_in[3];   // [128, 256]
    const float* gate_b2 = (const float*)d_in[4];   // [128]
    const float* W1      = (const float*)d_in[5];   // [3072, 768]
    const float* b1      = (const float*)d_in[6];   // [3072]
    const float* W2      = (const float*)d_in[7];   // [768, 3072]
    const float* b2      = (const float*)d_in[8];   // [768]
    const float* U1      = (const float*)d_in[9];   // [128, 3072]
    const float* SVH1    = (const float*)d_in[10];  // [128, 768]
    const float* U2      = (const float*)d_in[11];  // [128, 768]
    const float* SVH2    = (const float*)d_in[12];  // [128, 3072]
    const float* TB1     = (const float*)d_in[13];  // [8, 3072]
    const float* TB2     = (const float*)d_in[14];  // [8, 768]
    float* out = (float*)d_out;                     // [8192, 768] fp32

    char* p = (char*)d_ws;
    auto alloc = [&](size_t bytes) {
        char* q = p;
        p += (bytes + 255) & ~(size_t)255;
        return q;
    };
    bf16* hbuf  = (bf16*)alloc((size_t)8192 * 3072 * 2);  // fc1 output h (relu'd)
    bf16* xb    = (bf16*)alloc((size_t)8192 * 768 * 2);
    bf16* gbuf  = (bf16*)alloc((size_t)8192 * 256 * 2);
    bf16* g2buf = (bf16*)alloc((size_t)8192 * 128 * 2);
    bf16* t1buf = (bf16*)alloc((size_t)8192 * 128 * 2);
    bf16* t2buf = (bf16*)alloc((size_t)8192 * 128 * 2);
    bf16* W1b   = (bf16*)alloc((size_t)3072 * 768 * 2);
    bf16* W2b   = (bf16*)alloc((size_t)768 * 3072 * 2);
    bf16* gw1b  = (bf16*)alloc((size_t)256 * 768 * 2);
    bf16* gw2b  = (bf16*)alloc((size_t)128 * 256 * 2);
    bf16* svh1b = (bf16*)alloc((size_t)128 * 768 * 2);
    bf16* svh2b = (bf16*)alloc((size_t)128 * 3072 * 2);
    bf16* U1T   = (bf16*)alloc((size_t)3072 * 128 * 2);
    bf16* U2T   = (bf16*)alloc((size_t)768 * 128 * 2);
    float* gw   = (float*)alloc(2048 * 4);                // [16, 128]
    float* b1m  = (float*)alloc(3072 * 4);
    float* b2m  = (float*)alloc(768 * 4);
    float* t2parts = (float*)alloc((size_t)4 * 8192 * 128 * 4);  // post-fc1 partials
    // pre-fc1 split-K partials alias hbuf (hbuf not live until fc1): 16.8MB <= 50MB
    float* preparts = (float*)hbuf;

    const dim3 blk(256);

    // fp32 -> bf16 working copies
    cvt_kernel<<<6144, blk, 0, stream>>>(x, xb, 1572864);
    cvt_kernel<<<2304, blk, 0, stream>>>(W1, W1b, 589824);
    cvt_kernel<<<2304, blk, 0, stream>>>(W2, W2b, 589824);
    cvt_kernel<<<192,  blk, 0, stream>>>(gate_w1, gw1b, 49152);
    cvt_kernel<<<32,   blk, 0, stream>>>(gate_w2, gw2b, 8192);
    cvt_kernel<<<96,   blk, 0, stream>>>(SVH1, svh1b, 24576);
    cvt_kernel<<<384,  blk, 0, stream>>>(SVH2, svh2b, 98304);
    transpose_kernel<<<1536, blk, 0, stream>>>(U1, U2, U1T, U2T);
    prep_b_kernel<<<15, blk, 0, stream>>>(b1, TB1, b2, TB2, b1m, b2m);

    // router: g = relu(x @ gate_w1^T + gate_b1)    [8192, 256]
    gemm_bt<<<dim3(64, 2), blk, 0, stream>>>(xb, 768, 768, nullptr, 0, 0,
                                             gw1b, 768, nullptr, 0,
                                             gate_b1, nullptr, 1, gbuf, nullptr, 256);
    // g2 = g @ gate_w2^T + gate_b2   (split-K=4)   [8192, 128]
    gemm_splitk<<<dim3(64, 1, 4), blk, 0, stream>>>(gbuf, 256, gw2b, 256, 1, preparts);
    combine_kernel<<<4096, blk, 0, stream>>>(preparts, 4, 8192 * 128, 7,
                                             gate_b2, nullptr, 0, g2buf);
    // gw = mean_s(g2)                              [16, 128]
    mean_g2_kernel<<<16, 128, 0, stream>>>(g2buf, gw);

    // t1 = (x @ SVH1^T) * gw         (split-K=4)   [8192, 128]
    gemm_splitk<<<dim3(64, 1, 4), blk, 0, stream>>>(xb, 768, svh1b, 768, 3, preparts);
    combine_kernel<<<4096, blk, 0, stream>>>(preparts, 4, 8192 * 128, 7,
                                             nullptr, gw, 0, t1buf);
    // h = relu([x|t1] @ [W1|U1T]^T + b1m)          [8192, 3072]
    gemm_bt<<<dim3(64, 24), blk, 0, stream>>>(xb, 768, 768, t1buf, 128, 128,
                                              W1b, 768, U1T, 128,
                                              b1m, nullptr, 1, hbuf, nullptr, 3072);
    // t2 = (h @ SVH2^T) * gw         (split-K=4)   [8192, 128]
    gemm_splitk<<<dim3(64, 1, 4), blk, 0, stream>>>(hbuf, 3072, svh2b, 3072, 12, t2parts);
    combine_kernel<<<4096, blk, 0, stream>>>(t2parts, 4, 8192 * 128, 7,
                                             nullptr, gw, 0, t2buf);
    // out = [h|t2] @ [W2|U2T]^T + b2m  (fp32 out)  [8192, 768]
    gemm_bt<<<dim3(64, 6), blk, 0, stream>>>(hbuf, 3072, 3072, t2buf, 128, 128,
                                             W2b, 3072, U2T, 128,
                                             b2m, nullptr, 0, nullptr, out, 768);
}

// Round 5
// 314.054 us; speedup vs baseline: 2.7982x; 1.2234x over previous
//
#include <hip/hip_runtime.h>
#include <hip/hip_bf16.h>

using bf16 = __hip_bfloat16;
typedef __bf16 bf16x8 __attribute__((ext_vector_type(8)));
typedef __bf16 bf16x4 __attribute__((ext_vector_type(4)));
typedef float f32x4 __attribute__((ext_vector_type(4)));

#define BM 128
#define BN 128
#define BK 64

// ---------------------------------------------------------------------------
// Staging helper: 16B per lane via global_load_lds, wave-uniform LDS base.
// ---------------------------------------------------------------------------
__device__ __forceinline__ void stage16(const bf16* gsrc, bf16* lds_base)
{
    __builtin_amdgcn_global_load_lds(
        (__attribute__((address_space(1))) void*)(void*)gsrc,
        (__attribute__((address_space(3))) void*)(void*)lds_base,
        16, 0, 0);
}

// LDS chunk swizzle: slot (row, c) holds global chunk (row, c^(row&7)).
// Kills the 16-way ds_read_b128 bank conflict (row*128B strides alias all
// rows onto the same banks); XOR spreads the 16 r-lanes over 8 chunk slots.
// Staging permutes the SOURCE (lane fetches global chunk (L&7)^(row&7)), so
// the wave-uniform-base constraint of global_load_lds is preserved.

// ---------------------------------------------------------------------------
// 128x128 tiled MFMA GEMM: C = act(A @ B^T + bias), bf16 operands.
// Two K-segments (dense weight | rank-128 delta). fp32 out via Cf, else bf16 C.
// gscale (fp32 [16,128]): multiply by gscale[(row>>9)*128 + col].
// M%128==0, N%128==0, K0%64==0, K1%64==0. Block=256 (4 waves, 2x2).
// ---------------------------------------------------------------------------
__global__ __launch_bounds__(256)
void gemm_bt(const bf16* __restrict__ A0, int lda0, int K0,
             const bf16* __restrict__ A1, int lda1, int K1,
             const bf16* __restrict__ B0, int ldb0,
             const bf16* __restrict__ B1, int ldb1,
             const float* __restrict__ bias,
             const float* __restrict__ gscale,
             int relu,
             bf16* __restrict__ C, float* __restrict__ Cf, int ldc)
{
    __shared__ bf16 sA[BM * BK];
    __shared__ bf16 sB[BN * BK];

    const int t = threadIdx.x;
    const int w = t >> 6;
    const int l = t & 63;
    const int wm = w >> 1;
    const int wn = w & 1;
    const int r = l & 15;
    const int q = l >> 4;
    const int sw = r & 7;          // read-side swizzle key
    const int rowA0 = blockIdx.x * BM;
    const int rowB0 = blockIdx.y * BN;

    f32x4 acc[4][4];
#pragma unroll
    for (int i = 0; i < 4; ++i)
#pragma unroll
        for (int j = 0; j < 4; ++j)
            acc[i][j] = (f32x4){0.f, 0.f, 0.f, 0.f};

    const int nK = (K0 + K1) >> 6;
    for (int kt = 0; kt < nK; ++kt) {
        const int k0 = kt << 6;
        const bf16 *Ap, *Bp;
        int la, lb, ks;
        if (k0 < K0) { Ap = A0; la = lda0; Bp = B0; lb = ldb0; ks = k0; }
        else         { Ap = A1; la = lda1; Bp = B1; lb = ldb1; ks = k0 - K0; }

        __syncthreads();
#pragma unroll
        for (int it = 0; it < 4; ++it) {
            const int L   = it * 256 + t;
            const int row = L >> 3;
            const int cb  = (L & 7) ^ (row & 7);   // swizzled source chunk
            stage16(Ap + (size_t)(rowA0 + row) * la + ks + cb * 8,
                    sA + (size_t)(it * 256 + (w << 6)) * 8);
            stage16(Bp + (size_t)(rowB0 + row) * lb + ks + cb * 8,
                    sB + (size_t)(it * 256 + (w << 6)) * 8);
        }
        __syncthreads();

#pragma unroll
        for (int kk = 0; kk < 2; ++kk) {
            const int ch = ((kk * 4 + q) ^ sw) * 8;
            bf16x8 aF[4], bF[4];
#pragma unroll
            for (int i = 0; i < 4; ++i)
                aF[i] = *(const bf16x8*)&sA[(wm * 64 + i * 16 + r) * BK + ch];
#pragma unroll
            for (int j = 0; j < 4; ++j)
                bF[j] = *(const bf16x8*)&sB[(wn * 64 + j * 16 + r) * BK + ch];
#pragma unroll
            for (int i = 0; i < 4; ++i)
#pragma unroll
                for (int j = 0; j < 4; ++j)
                    acc[i][j] = __builtin_amdgcn_mfma_f32_16x16x32_bf16(
                        aF[i], bF[j], acc[i][j], 0, 0, 0);
        }
    }

    // C/D layout: col = lane&15, row = quad*4 + reg (m89/m91 verified)
#pragma unroll
    for (int i = 0; i < 4; ++i)
#pragma unroll
        for (int j = 0; j < 4; ++j)
#pragma unroll
            for (int rr = 0; rr < 4; ++rr) {
                const int row = rowA0 + wm * 64 + i * 16 + q * 4 + rr;
                const int col = rowB0 + wn * 64 + j * 16 + r;
                float v = acc[i][j][rr];
                if (bias)   v += bias[col];
                if (gscale) v *= gscale[(row >> 9) * 128 + col];
                if (relu)   v = v > 0.f ? v : 0.f;
                if (Cf) Cf[(size_t)row * ldc + col] = v;
                else    C[(size_t)row * ldc + col] = __float2bfloat16(v);
            }
}

// ---------------------------------------------------------------------------
// 64x128 tile variant (BM=64): doubles block count for N<=768 GEMMs (fc2,
// router g1) so CU coverage isn't the limiter. 4 waves side-by-side (1x4),
// each wave owns 64x32 of C. LDS 24KB -> 6 blocks/CU.
// ---------------------------------------------------------------------------
__global__ __launch_bounds__(256)
void gemm_bt64(const bf16* __restrict__ A0, int lda0, int K0,
               const bf16* __restrict__ A1, int lda1, int K1,
               const bf16* __restrict__ B0, int ldb0,
               const bf16* __restrict__ B1, int ldb1,
               const float* __restrict__ bias,
               const float* __restrict__ gscale,
               int relu,
               bf16* __restrict__ C, float* __restrict__ Cf, int ldc)
{
    __shared__ bf16 sA[64 * BK];
    __shared__ bf16 sB[BN * BK];

    const int t = threadIdx.x;
    const int w = t >> 6;
    const int l = t & 63;
    const int wn = w;              // wave col (0..3), 32 cols each
    const int r = l & 15;
    const int q = l >> 4;
    const int sw = r & 7;
    const int rowA0 = blockIdx.x * 64;
    const int rowB0 = blockIdx.y * BN;

    f32x4 acc[4][2];
#pragma unroll
    for (int i = 0; i < 4; ++i)
#pragma unroll
        for (int j = 0; j < 2; ++j)
            acc[i][j] = (f32x4){0.f, 0.f, 0.f, 0.f};

    const int nK = (K0 + K1) >> 6;
    for (int kt = 0; kt < nK; ++kt) {
        const int k0 = kt << 6;
        const bf16 *Ap, *Bp;
        int la, lb, ks;
        if (k0 < K0) { Ap = A0; la = lda0; Bp = B0; lb = ldb0; ks = k0; }
        else         { Ap = A1; la = lda1; Bp = B1; lb = ldb1; ks = k0 - K0; }

        __syncthreads();
#pragma unroll
        for (int it = 0; it < 2; ++it) {        // A: 64 rows = 512 chunks
            const int L   = it * 256 + t;
            const int row = L >> 3;
            const int cb  = (L & 7) ^ (row & 7);
            stage16(Ap + (size_t)(rowA0 + row) * la + ks + cb * 8,
                    sA + (size_t)(it * 256 + (w << 6)) * 8);
        }
#pragma unroll
        for (int it = 0; it < 4; ++it) {        // B: 128 rows = 1024 chunks
            const int L   = it * 256 + t;
            const int row = L >> 3;
            const int cb  = (L & 7) ^ (row & 7);
            stage16(Bp + (size_t)(rowB0 + row) * lb + ks + cb * 8,
                    sB + (size_t)(it * 256 + (w << 6)) * 8);
        }
        __syncthreads();

#pragma unroll
        for (int kk = 0; kk < 2; ++kk) {
            const int ch = ((kk * 4 + q) ^ sw) * 8;
            bf16x8 aF[4], bF[2];
#pragma unroll
            for (int i = 0; i < 4; ++i)
                aF[i] = *(const bf16x8*)&sA[(i * 16 + r) * BK + ch];
#pragma unroll
            for (int j = 0; j < 2; ++j)
                bF[j] = *(const bf16x8*)&sB[(wn * 32 + j * 16 + r) * BK + ch];
#pragma unroll
            for (int i = 0; i < 4; ++i)
#pragma unroll
                for (int j = 0; j < 2; ++j)
                    acc[i][j] = __builtin_amdgcn_mfma_f32_16x16x32_bf16(
                        aF[i], bF[j], acc[i][j], 0, 0, 0);
        }
    }

#pragma unroll
    for (int i = 0; i < 4; ++i)
#pragma unroll
        for (int j = 0; j < 2; ++j)
#pragma unroll
            for (int rr = 0; rr < 4; ++rr) {
                const int row = rowA0 + i * 16 + q * 4 + rr;
                const int col = rowB0 + wn * 32 + j * 16 + r;
                float v = acc[i][j][rr];
                if (bias)   v += bias[col];
                if (gscale) v *= gscale[(row >> 9) * 128 + col];
                if (relu)   v = v > 0.f ? v : 0.f;
                if (Cf) Cf[(size_t)row * ldc + col] = v;
                else    C[(size_t)row * ldc + col] = __float2bfloat16(v);
            }
}

// ---------------------------------------------------------------------------
// Split-K GEMM for thin-N (N=128) products. grid (M/128, 1, S). Deterministic
// fp32 partials; combine applies bias/gscale.
// ---------------------------------------------------------------------------
__global__ __launch_bounds__(256)
void gemm_splitk(const bf16* __restrict__ A, int lda,
                 const bf16* __restrict__ B, int ldb,
                 int ktiles_per, float* __restrict__ Cpart)
{
    __shared__ bf16 sA[BM * BK];
    __shared__ bf16 sB[BN * BK];

    const int t = threadIdx.x;
    const int w = t >> 6;
    const int l = t & 63;
    const int wm = w >> 1;
    const int wn = w & 1;
    const int r = l & 15;
    const int q = l >> 4;
    const int sw = r & 7;
    const int rowA0 = blockIdx.x * BM;
    const int rowB0 = blockIdx.y * BN;
    const int M = gridDim.x * BM;
    const int N = gridDim.y * BN;
    const int ksbase = blockIdx.z * ktiles_per * BK;

    f32x4 acc[4][4];
#pragma unroll
    for (int i = 0; i < 4; ++i)
#pragma unroll
        for (int j = 0; j < 4; ++j)
            acc[i][j] = (f32x4){0.f, 0.f, 0.f, 0.f};

    for (int kt = 0; kt < ktiles_per; ++kt) {
        const int ks = ksbase + kt * BK;

        __syncthreads();
#pragma unroll
        for (int it = 0; it < 4; ++it) {
            const int L   = it * 256 + t;
            const int row = L >> 3;
            const int cb  = (L & 7) ^ (row & 7);
            stage16(A + (size_t)(rowA0 + row) * lda + ks + cb * 8,
                    sA + (size_t)(it * 256 + (w << 6)) * 8);
            stage16(B + (size_t)(rowB0 + row) * ldb + ks + cb * 8,
                    sB + (size_t)(it * 256 + (w << 6)) * 8);
        }
        __syncthreads();

#pragma unroll
        for (int kk = 0; kk < 2; ++kk) {
            const int ch = ((kk * 4 + q) ^ sw) * 8;
            bf16x8 aF[4], bF[4];
#pragma unroll
            for (int i = 0; i < 4; ++i)
                aF[i] = *(const bf16x8*)&sA[(wm * 64 + i * 16 + r) * BK + ch];
#pragma unroll
            for (int j = 0; j < 4; ++j)
                bF[j] = *(const bf16x8*)&sB[(wn * 64 + j * 16 + r) * BK + ch];
#pragma unroll
            for (int i = 0; i < 4; ++i)
#pragma unroll
                for (int j = 0; j < 4; ++j)
                    acc[i][j] = __builtin_amdgcn_mfma_f32_16x16x32_bf16(
                        aF[i], bF[j], acc[i][j], 0, 0, 0);
        }
    }

    float* Cz = Cpart + (size_t)blockIdx.z * M * N;
#pragma unroll
    for (int i = 0; i < 4; ++i)
#pragma unroll
        for (int j = 0; j < 4; ++j)
#pragma unroll
            for (int rr = 0; rr < 4; ++rr) {
                const int row = rowA0 + wm * 64 + i * 16 + q * 4 + rr;
                const int col = rowB0 + wn * 64 + j * 16 + r;
                Cz[(size_t)row * N + col] = acc[i][j][rr];
            }
}

// sum S partials + bias + gscale + relu -> bf16 (N = 1<<nshift)
__global__ void combine_kernel(const float* __restrict__ parts, int S,
                               int MN, int nshift,
                               const float* __restrict__ bias,
                               const float* __restrict__ gscale,
                               int relu, bf16* __restrict__ outb)
{
    const int i = blockIdx.x * 256 + threadIdx.x;
    if (i >= MN) return;
    const int col = i & ((1 << nshift) - 1);
    const int row = i >> nshift;
    float s = 0.f;
    for (int z = 0; z < S; ++z) s += parts[(size_t)z * MN + i];
    if (bias)   s += bias[col];
    if (gscale) s *= gscale[(row >> 9) * 128 + col];
    if (relu)   s = s > 0.f ? s : 0.f;
    outb[i] = __float2bfloat16(s);
}

// ---------------------------------------------------------------------------
// Fused prep: all fp32->bf16 casts + U transposes + merged biases. 1 launch.
// ---------------------------------------------------------------------------
__device__ __forceinline__ void cvt_range(const float* src, bf16* dst, int base, int t)
{
    const int i = base * 256 + t;
    const float4 v = ((const float4*)src)[i];
    ((bf16x4*)dst)[i] = (bf16x4){(__bf16)v.x, (__bf16)v.y, (__bf16)v.z, (__bf16)v.w};
}

__global__ void prep_all(const float* __restrict__ x,    bf16* __restrict__ xb,
                         const float* __restrict__ W1,   bf16* __restrict__ W1b,
                         const float* __restrict__ W2,   bf16* __restrict__ W2b,
                         const float* __restrict__ gw1,  bf16* __restrict__ gw1b,
                         const float* __restrict__ gw2,  bf16* __restrict__ gw2b,
                         const float* __restrict__ SVH1, bf16* __restrict__ svh1b,
                         const float* __restrict__ SVH2, bf16* __restrict__ svh2b,
                         const float* __restrict__ U1,   bf16* __restrict__ U1T,
                         const float* __restrict__ U2,   bf16* __restrict__ U2T,
                         const float* __restrict__ b1,   const float* __restrict__ TB1,
                         const float* __restrict__ b2,   const float* __restrict__ TB2,
                         float* __restrict__ b1m, float* __restrict__ b2m)
{
    const int b = blockIdx.x;
    const int t = threadIdx.x;
    if      (b < 6144)  cvt_range(x,   xb,   b,         t);
    else if (b < 8448)  cvt_range(W1,  W1b,  b - 6144,  t);
    else if (b < 10752) cvt_range(W2,  W2b,  b - 8448,  t);
    else if (b < 10944) cvt_range(gw1, gw1b, b - 10752, t);
    else if (b < 10976) cvt_range(gw2, gw2b, b - 10944, t);
    else if (b < 11072) cvt_range(SVH1, svh1b, b - 10976, t);
    else if (b < 11456) cvt_range(SVH2, svh2b, b - 11072, t);
    else if (b < 12992) {
        const int i = (b - 11456) * 256 + t;
        if (i < 3072 * 128) {
            const int f = i >> 7, ek = i & 127;
            U1T[i] = __float2bfloat16(U1[ek * 3072 + f]);
        }
        if (i < 768 * 128) {
            const int h = i >> 7, ek = i & 127;
            U2T[i] = __float2bfloat16(U2[ek * 768 + h]);
        }
    } else {
        const int i = (b - 12992) * 256 + t;
        if (i < 3072) {
            float s = 0.f;
            for (int e = 0; e < 8; ++e) s += TB1[e * 3072 + i];
            b1m[i] = b1[i] + 0.2f * s;
        } else if (i < 3840) {
            const int j = i - 3072;
            float s = 0.f;
            for (int e = 0; e < 8; ++e) s += TB2[e * 768 + j];
            b2m[j] = b2[j] + 0.2f * s;
        }
    }
}

// gmean[b, c] = mean_s g[b, s, c]  (g already relu'd), c in [0,256)
__global__ void mean_g1_kernel(const bf16* __restrict__ g, float* __restrict__ gmean)
{
    const int b = blockIdx.x;
    const int c = threadIdx.x;     // 0..255
    float s = 0.f;
    for (int si = 0; si < 512; ++si)
        s += __bfloat162float(g[(size_t)(b * 512 + si) * 256 + c]);
    gmean[b * 256 + c] = s * (1.0f / 512.0f);
}

// gw[b, c] = gmean[b,:] . gate_w2[c,:] + gate_b2[c]
// (mean commutes with the linear layer: mean_s(g@W^T+b) = mean_s(g)@W^T+b)
__global__ void gw_kernel(const float* __restrict__ gmean, const bf16* __restrict__ gw2b,
                          const float* __restrict__ gate_b2, float* __restrict__ gw)
{
    const int b = blockIdx.x;
    const int c = threadIdx.x;     // 0..127
    float s = gate_b2[c];
    for (int j = 0; j < 256; ++j)
        s += gmean[b * 256 + j] * __bfloat162float(gw2b[c * 256 + j]);
    gw[b * 128 + c] = s;
}

// ---------------------------------------------------------------------------
extern "C" void kernel_launch(void* const* d_in, const int* in_sizes, int n_in,
                              void* d_out, int out_size, void* d_ws, size_t ws_size,
                              hipStream_t stream)
{
    const float* x       = (const float*)d_in[0];
    const float* gate_w1 = (const float*)d_in[1];
    const float* gate_b1 = (const float*)d_in[2];
    const float* gate_w2 = (const float*)d_in[3];
    const float* gate_b2 = (const float*)d_in[4];
    const float* W1      = (const float*)d_in[5];
    const float* b1      = (const float*)d_in[6];
    const float* W2      = (const float*)d_in[7];
    const float* b2      = (const float*)d_in[8];
    const float* U1      = (const float*)d_in[9];
    const float* SVH1    = (const float*)d_in[10];
    const float* U2      = (const float*)d_in[11];
    const float* SVH2    = (const float*)d_in[12];
    const float* TB1     = (const float*)d_in[13];
    const float* TB2     = (const float*)d_in[14];
    float* out = (float*)d_out;                     // [8192, 768] fp32

    char* p = (char*)d_ws;
    auto alloc = [&](size_t bytes) {
        char* q = p;
        p += (bytes + 255) & ~(size_t)255;
        return q;
    };
    bf16* hbuf  = (bf16*)alloc((size_t)8192 * 3072 * 2);
    bf16* xb    = (bf16*)alloc((size_t)8192 * 768 * 2);
    bf16* gbuf  = (bf16*)alloc((size_t)8192 * 256 * 2);
    bf16* t1buf = (bf16*)alloc((size_t)8192 * 128 * 2);
    bf16* t2buf = (bf16*)alloc((size_t)8192 * 128 * 2);
    bf16* W1b   = (bf16*)alloc((size_t)3072 * 768 * 2);
    bf16* W2b   = (bf16*)alloc((size_t)768 * 3072 * 2);
    bf16* gw1b  = (bf16*)alloc((size_t)256 * 768 * 2);
    bf16* gw2b  = (bf16*)alloc((size_t)128 * 256 * 2);
    bf16* svh1b = (bf16*)alloc((size_t)128 * 768 * 2);
    bf16* svh2b = (bf16*)alloc((size_t)128 * 3072 * 2);
    bf16* U1T   = (bf16*)alloc((size_t)3072 * 128 * 2);
    bf16* U2T   = (bf16*)alloc((size_t)768 * 128 * 2);
    float* gmean = (float*)alloc(16 * 256 * 4);
    float* gw   = (float*)alloc(2048 * 4);
    float* b1m  = (float*)alloc(3072 * 4);
    float* b2m  = (float*)alloc(768 * 4);
    float* t2parts = (float*)alloc((size_t)4 * 8192 * 128 * 4);
    float* preparts = (float*)hbuf;   // alias: hbuf not live until fc1

    const dim3 blk(256);

    prep_all<<<13007, blk, 0, stream>>>(x, xb, W1, W1b, W2, W2b,
                                        gate_w1, gw1b, gate_w2, gw2b,
                                        SVH1, svh1b, SVH2, svh2b,
                                        U1, U1T, U2, U2T,
                                        b1, TB1, b2, TB2, b1m, b2m);

    // router: g = relu(x @ gate_w1^T + gate_b1)        [8192, 256]
    gemm_bt64<<<dim3(128, 2), blk, 0, stream>>>(xb, 768, 768, nullptr, 0, 0,
                                                gw1b, 768, nullptr, 0,
                                                gate_b1, nullptr, 1, gbuf, nullptr, 256);
    // gw = mean_s(g) @ gate_w2^T + gate_b2             [16, 128]
    mean_g1_kernel<<<16, 256, 0, stream>>>(gbuf, gmean);
    gw_kernel<<<16, 128, 0, stream>>>(gmean, gw2b, gate_b2, gw);

    // t1 = (x @ SVH1^T) * gw      (split-K=4)          [8192, 128]
    gemm_splitk<<<dim3(64, 1, 4), blk, 0, stream>>>(xb, 768, svh1b, 768, 3, preparts);
    combine_kernel<<<4096, blk, 0, stream>>>(preparts, 4, 8192 * 128, 7,
                                             nullptr, gw, 0, t1buf);
    // h = relu([x|t1] @ [W1|U1T]^T + b1m)              [8192, 3072]
    gemm_bt<<<dim3(64, 24), blk, 0, stream>>>(xb, 768, 768, t1buf, 128, 128,
                                              W1b, 768, U1T, 128,
                                              b1m, nullptr, 1, hbuf, nullptr, 3072);
    // t2 = (h @ SVH2^T) * gw      (split-K=4)          [8192, 128]
    gemm_splitk<<<dim3(64, 1, 4), blk, 0, stream>>>(hbuf, 3072, svh2b, 3072, 12, t2parts);
    combine_kernel<<<4096, blk, 0, stream>>>(t2parts, 4, 8192 * 128, 7,
                                             nullptr, gw, 0, t2buf);
    // out = [h|t2] @ [W2|U2T]^T + b2m  (fp32 out)      [8192, 768]
    gemm_bt64<<<dim3(128, 6), blk, 0, stream>>>(hbuf, 3072, 3072, t2buf, 128, 128,
                                                W2b, 3072, U2T, 128,
                                                b2m, nullptr, 0, nullptr, out, 768);
}

// Round 6
// 306.540 us; speedup vs baseline: 2.8668x; 1.0245x over previous
//
#include <hip/hip_runtime.h>
#include <hip/hip_bf16.h>

using bf16 = __hip_bfloat16;
typedef __bf16 bf16x8 __attribute__((ext_vector_type(8)));
typedef __bf16 bf16x4 __attribute__((ext_vector_type(4)));
typedef float f32x4 __attribute__((ext_vector_type(4)));

#define BM 128
#define BN 128
#define BK 64

// ---------------------------------------------------------------------------
// Staging helper: 16B per lane via global_load_lds, wave-uniform LDS base.
// ---------------------------------------------------------------------------
__device__ __forceinline__ void stage16(const bf16* gsrc, bf16* lds_base)
{
    __builtin_amdgcn_global_load_lds(
        (__attribute__((address_space(1))) void*)(void*)gsrc,
        (__attribute__((address_space(3))) void*)(void*)lds_base,
        16, 0, 0);
}

// LDS chunk swizzle: slot (row, c) holds global chunk (row, c^(row&7)).
// Kills the 16-way ds_read_b128 bank conflict (conflicts 1.65e7 -> 0, R5).

// ---------------------------------------------------------------------------
// 128x128 tiled MFMA GEMM: C = act(A @ B^T + bias), bf16 operands.
// Two K-segments (dense weight | rank-128 delta). fp32 out via Cf, else bf16 C.
// gscale (fp32 [16,128]): multiply by gscale[(row>>9)*128 + col].
// M%128==0, N%128==0, K0%64==0, K1%64==0. Block=256 (4 waves, 2x2).
// ---------------------------------------------------------------------------
__global__ __launch_bounds__(256)
void gemm_bt(const bf16* __restrict__ A0, int lda0, int K0,
             const bf16* __restrict__ A1, int lda1, int K1,
             const bf16* __restrict__ B0, int ldb0,
             const bf16* __restrict__ B1, int ldb1,
             const float* __restrict__ bias,
             const float* __restrict__ gscale,
             int relu,
             bf16* __restrict__ C, float* __restrict__ Cf, int ldc)
{
    __shared__ bf16 sA[BM * BK];
    __shared__ bf16 sB[BN * BK];

    const int t = threadIdx.x;
    const int w = t >> 6;
    const int l = t & 63;
    const int wm = w >> 1;
    const int wn = w & 1;
    const int r = l & 15;
    const int q = l >> 4;
    const int sw = r & 7;
    const int rowA0 = blockIdx.x * BM;
    const int rowB0 = blockIdx.y * BN;

    f32x4 acc[4][4];
#pragma unroll
    for (int i = 0; i < 4; ++i)
#pragma unroll
        for (int j = 0; j < 4; ++j)
            acc[i][j] = (f32x4){0.f, 0.f, 0.f, 0.f};

    const int nK = (K0 + K1) >> 6;
    for (int kt = 0; kt < nK; ++kt) {
        const int k0 = kt << 6;
        const bf16 *Ap, *Bp;
        int la, lb, ks;
        if (k0 < K0) { Ap = A0; la = lda0; Bp = B0; lb = ldb0; ks = k0; }
        else         { Ap = A1; la = lda1; Bp = B1; lb = ldb1; ks = k0 - K0; }

        __syncthreads();
#pragma unroll
        for (int it = 0; it < 4; ++it) {
            const int L   = it * 256 + t;
            const int row = L >> 3;
            const int cb  = (L & 7) ^ (row & 7);   // swizzled source chunk
            stage16(Ap + (size_t)(rowA0 + row) * la + ks + cb * 8,
                    sA + (size_t)(it * 256 + (w << 6)) * 8);
            stage16(Bp + (size_t)(rowB0 + row) * lb + ks + cb * 8,
                    sB + (size_t)(it * 256 + (w << 6)) * 8);
        }
        __syncthreads();

#pragma unroll
        for (int kk = 0; kk < 2; ++kk) {
            const int ch = ((kk * 4 + q) ^ sw) * 8;
            bf16x8 aF[4], bF[4];
#pragma unroll
            for (int i = 0; i < 4; ++i)
                aF[i] = *(const bf16x8*)&sA[(wm * 64 + i * 16 + r) * BK + ch];
#pragma unroll
            for (int j = 0; j < 4; ++j)
                bF[j] = *(const bf16x8*)&sB[(wn * 64 + j * 16 + r) * BK + ch];
#pragma unroll
            for (int i = 0; i < 4; ++i)
#pragma unroll
                for (int j = 0; j < 4; ++j)
                    acc[i][j] = __builtin_amdgcn_mfma_f32_16x16x32_bf16(
                        aF[i], bF[j], acc[i][j], 0, 0, 0);
        }
    }

    // C/D layout: col = lane&15, row = quad*4 + reg (m89/m91 verified)
#pragma unroll
    for (int i = 0; i < 4; ++i)
#pragma unroll
        for (int j = 0; j < 4; ++j)
#pragma unroll
            for (int rr = 0; rr < 4; ++rr) {
                const int row = rowA0 + wm * 64 + i * 16 + q * 4 + rr;
                const int col = rowB0 + wn * 64 + j * 16 + r;
                float v = acc[i][j][rr];
                if (bias)   v += bias[col];
                if (gscale) v *= gscale[(row >> 9) * 128 + col];
                if (relu)   v = v > 0.f ? v : 0.f;
                if (Cf) Cf[(size_t)row * ldc + col] = v;
                else    C[(size_t)row * ldc + col] = __float2bfloat16(v);
            }
}

// ---------------------------------------------------------------------------
// 64x128 tile variant (BM=64): doubles block count for N<=768 GEMMs (fc2).
// 4 waves side-by-side (1x4), each wave owns 64x32 of C.
// ---------------------------------------------------------------------------
__global__ __launch_bounds__(256)
void gemm_bt64(const bf16* __restrict__ A0, int lda0, int K0,
               const bf16* __restrict__ A1, int lda1, int K1,
               const bf16* __restrict__ B0, int ldb0,
               const bf16* __restrict__ B1, int ldb1,
               const float* __restrict__ bias,
               const float* __restrict__ gscale,
               int relu,
               bf16* __restrict__ C, float* __restrict__ Cf, int ldc)
{
    __shared__ bf16 sA[64 * BK];
    __shared__ bf16 sB[BN * BK];

    const int t = threadIdx.x;
    const int w = t >> 6;
    const int l = t & 63;
    const int wn = w;
    const int r = l & 15;
    const int q = l >> 4;
    const int sw = r & 7;
    const int rowA0 = blockIdx.x * 64;
    const int rowB0 = blockIdx.y * BN;

    f32x4 acc[4][2];
#pragma unroll
    for (int i = 0; i < 4; ++i)
#pragma unroll
        for (int j = 0; j < 2; ++j)
            acc[i][j] = (f32x4){0.f, 0.f, 0.f, 0.f};

    const int nK = (K0 + K1) >> 6;
    for (int kt = 0; kt < nK; ++kt) {
        const int k0 = kt << 6;
        const bf16 *Ap, *Bp;
        int la, lb, ks;
        if (k0 < K0) { Ap = A0; la = lda0; Bp = B0; lb = ldb0; ks = k0; }
        else         { Ap = A1; la = lda1; Bp = B1; lb = ldb1; ks = k0 - K0; }

        __syncthreads();
#pragma unroll
        for (int it = 0; it < 2; ++it) {
            const int L   = it * 256 + t;
            const int row = L >> 3;
            const int cb  = (L & 7) ^ (row & 7);
            stage16(Ap + (size_t)(rowA0 + row) * la + ks + cb * 8,
                    sA + (size_t)(it * 256 + (w << 6)) * 8);
        }
#pragma unroll
        for (int it = 0; it < 4; ++it) {
            const int L   = it * 256 + t;
            const int row = L >> 3;
            const int cb  = (L & 7) ^ (row & 7);
            stage16(Bp + (size_t)(rowB0 + row) * lb + ks + cb * 8,
                    sB + (size_t)(it * 256 + (w << 6)) * 8);
        }
        __syncthreads();

#pragma unroll
        for (int kk = 0; kk < 2; ++kk) {
            const int ch = ((kk * 4 + q) ^ sw) * 8;
            bf16x8 aF[4], bF[2];
#pragma unroll
            for (int i = 0; i < 4; ++i)
                aF[i] = *(const bf16x8*)&sA[(i * 16 + r) * BK + ch];
#pragma unroll
            for (int j = 0; j < 2; ++j)
                bF[j] = *(const bf16x8*)&sB[(wn * 32 + j * 16 + r) * BK + ch];
#pragma unroll
            for (int i = 0; i < 4; ++i)
#pragma unroll
                for (int j = 0; j < 2; ++j)
                    acc[i][j] = __builtin_amdgcn_mfma_f32_16x16x32_bf16(
                        aF[i], bF[j], acc[i][j], 0, 0, 0);
        }
    }

#pragma unroll
    for (int i = 0; i < 4; ++i)
#pragma unroll
        for (int j = 0; j < 2; ++j)
#pragma unroll
            for (int rr = 0; rr < 4; ++rr) {
                const int row = rowA0 + i * 16 + q * 4 + rr;
                const int col = rowB0 + wn * 32 + j * 16 + r;
                float v = acc[i][j][rr];
                if (bias)   v += bias[col];
                if (gscale) v *= gscale[(row >> 9) * 128 + col];
                if (relu)   v = v > 0.f ? v : 0.f;
                if (Cf) Cf[(size_t)row * ldc + col] = v;
                else    C[(size_t)row * ldc + col] = __float2bfloat16(v);
            }
}

// ---------------------------------------------------------------------------
// Router GEMM with fused sequence-mean: computes relu(x@gw1^T + b) for its
// 64x128 tile and directly accumulates column sums into gsum[16,256] via
// one fp32 atomicAdd per column (g itself is never written — it's only
// consumed by mean_s). 64-row blocks never straddle a 512-row batch.
// ---------------------------------------------------------------------------
__global__ __launch_bounds__(256)
void g1sum_kernel(const bf16* __restrict__ A0, int lda0, int K0,
                  const bf16* __restrict__ B0, int ldb0,
                  const float* __restrict__ bias,
                  float* __restrict__ gsum)
{
    __shared__ bf16 sA[64 * BK];
    __shared__ bf16 sB[BN * BK];

    const int t = threadIdx.x;
    const int w = t >> 6;
    const int l = t & 63;
    const int wn = w;
    const int r = l & 15;
    const int q = l >> 4;
    const int sw = r & 7;
    const int rowA0 = blockIdx.x * 64;
    const int rowB0 = blockIdx.y * BN;
    const int b = rowA0 >> 9;      // batch of all 64 rows

    f32x4 acc[4][2];
#pragma unroll
    for (int i = 0; i < 4; ++i)
#pragma unroll
        for (int j = 0; j < 2; ++j)
            acc[i][j] = (f32x4){0.f, 0.f, 0.f, 0.f};

    const int nK = K0 >> 6;
    for (int kt = 0; kt < nK; ++kt) {
        const int ks = kt << 6;

        __syncthreads();
#pragma unroll
        for (int it = 0; it < 2; ++it) {
            const int L   = it * 256 + t;
            const int row = L >> 3;
            const int cb  = (L & 7) ^ (row & 7);
            stage16(A0 + (size_t)(rowA0 + row) * lda0 + ks + cb * 8,
                    sA + (size_t)(it * 256 + (w << 6)) * 8);
        }
#pragma unroll
        for (int it = 0; it < 4; ++it) {
            const int L   = it * 256 + t;
            const int row = L >> 3;
            const int cb  = (L & 7) ^ (row & 7);
            stage16(B0 + (size_t)(rowB0 + row) * ldb0 + ks + cb * 8,
                    sB + (size_t)(it * 256 + (w << 6)) * 8);
        }
        __syncthreads();

#pragma unroll
        for (int kk = 0; kk < 2; ++kk) {
            const int ch = ((kk * 4 + q) ^ sw) * 8;
            bf16x8 aF[4], bF[2];
#pragma unroll
            for (int i = 0; i < 4; ++i)
                aF[i] = *(const bf16x8*)&sA[(i * 16 + r) * BK + ch];
#pragma unroll
            for (int j = 0; j < 2; ++j)
                bF[j] = *(const bf16x8*)&sB[(wn * 32 + j * 16 + r) * BK + ch];
#pragma unroll
            for (int i = 0; i < 4; ++i)
#pragma unroll
                for (int j = 0; j < 2; ++j)
                    acc[i][j] = __builtin_amdgcn_mfma_f32_16x16x32_bf16(
                        aF[i], bF[j], acc[i][j], 0, 0, 0);
        }
    }

    // bias + relu + sum over this block's 64 rows, then cross-quad reduce.
#pragma unroll
    for (int j = 0; j < 2; ++j) {
        const int col = rowB0 + wn * 32 + j * 16 + r;
        const float bc = bias[col];
        float s = 0.f;
#pragma unroll
        for (int i = 0; i < 4; ++i)
#pragma unroll
            for (int rr = 0; rr < 4; ++rr) {
                const float v = acc[i][j][rr] + bc;
                s += v > 0.f ? v : 0.f;
            }
        s += __shfl_xor(s, 16, 64);    // reduce across q-pairs
        s += __shfl_xor(s, 32, 64);
        if (q == 0) atomicAdd(&gsum[b * 256 + col], s);
    }
}

// ---------------------------------------------------------------------------
// Split-K GEMM for thin-N (N=128) products (t2). Deterministic fp32 partials.
// ---------------------------------------------------------------------------
__global__ __launch_bounds__(256)
void gemm_splitk(const bf16* __restrict__ A, int lda,
                 const bf16* __restrict__ B, int ldb,
                 int ktiles_per, float* __restrict__ Cpart)
{
    __shared__ bf16 sA[BM * BK];
    __shared__ bf16 sB[BN * BK];

    const int t = threadIdx.x;
    const int w = t >> 6;
    const int l = t & 63;
    const int wm = w >> 1;
    const int wn = w & 1;
    const int r = l & 15;
    const int q = l >> 4;
    const int sw = r & 7;
    const int rowA0 = blockIdx.x * BM;
    const int rowB0 = blockIdx.y * BN;
    const int M = gridDim.x * BM;
    const int N = gridDim.y * BN;
    const int ksbase = blockIdx.z * ktiles_per * BK;

    f32x4 acc[4][4];
#pragma unroll
    for (int i = 0; i < 4; ++i)
#pragma unroll
        for (int j = 0; j < 4; ++j)
            acc[i][j] = (f32x4){0.f, 0.f, 0.f, 0.f};

    for (int kt = 0; kt < ktiles_per; ++kt) {
        const int ks = ksbase + kt * BK;

        __syncthreads();
#pragma unroll
        for (int it = 0; it < 4; ++it) {
            const int L   = it * 256 + t;
            const int row = L >> 3;
            const int cb  = (L & 7) ^ (row & 7);
            stage16(A + (size_t)(rowA0 + row) * lda + ks + cb * 8,
                    sA + (size_t)(it * 256 + (w << 6)) * 8);
            stage16(B + (size_t)(rowB0 + row) * ldb + ks + cb * 8,
                    sB + (size_t)(it * 256 + (w << 6)) * 8);
        }
        __syncthreads();

#pragma unroll
        for (int kk = 0; kk < 2; ++kk) {
            const int ch = ((kk * 4 + q) ^ sw) * 8;
            bf16x8 aF[4], bF[4];
#pragma unroll
            for (int i = 0; i < 4; ++i)
                aF[i] = *(const bf16x8*)&sA[(wm * 64 + i * 16 + r) * BK + ch];
#pragma unroll
            for (int j = 0; j < 4; ++j)
                bF[j] = *(const bf16x8*)&sB[(wn * 64 + j * 16 + r) * BK + ch];
#pragma unroll
            for (int i = 0; i < 4; ++i)
#pragma unroll
                for (int j = 0; j < 4; ++j)
                    acc[i][j] = __builtin_amdgcn_mfma_f32_16x16x32_bf16(
                        aF[i], bF[j], acc[i][j], 0, 0, 0);
        }
    }

    float* Cz = Cpart + (size_t)blockIdx.z * M * N;
#pragma unroll
    for (int i = 0; i < 4; ++i)
#pragma unroll
        for (int j = 0; j < 4; ++j)
#pragma unroll
            for (int rr = 0; rr < 4; ++rr) {
                const int row = rowA0 + wm * 64 + i * 16 + q * 4 + rr;
                const int col = rowB0 + wn * 64 + j * 16 + r;
                Cz[(size_t)row * N + col] = acc[i][j][rr];
            }
}

// sum S partials + gscale -> bf16 (N = 1<<nshift)
__global__ void combine_kernel(const float* __restrict__ parts, int S,
                               int MN, int nshift,
                               const float* __restrict__ gscale,
                               bf16* __restrict__ outb)
{
    const int i = blockIdx.x * 256 + threadIdx.x;
    if (i >= MN) return;
    const int col = i & ((1 << nshift) - 1);
    const int row = i >> nshift;
    float s = 0.f;
    for (int z = 0; z < S; ++z) s += parts[(size_t)z * MN + i];
    if (gscale) s *= gscale[(row >> 9) * 128 + col];
    outb[i] = __float2bfloat16(s);
}

// ---------------------------------------------------------------------------
// Fused prep: fp32->bf16 casts + U transposes + merged biases + gsum zero.
// ---------------------------------------------------------------------------
__device__ __forceinline__ void cvt_range(const float* src, bf16* dst, int base, int t)
{
    const int i = base * 256 + t;
    const float4 v = ((const float4*)src)[i];
    ((bf16x4*)dst)[i] = (bf16x4){(__bf16)v.x, (__bf16)v.y, (__bf16)v.z, (__bf16)v.w};
}

__global__ void prep_all(const float* __restrict__ x,    bf16* __restrict__ xb,
                         const float* __restrict__ W1,   bf16* __restrict__ W1b,
                         const float* __restrict__ W2,   bf16* __restrict__ W2b,
                         const float* __restrict__ gw1,  bf16* __restrict__ gw1b,
                         const float* __restrict__ gw2,  bf16* __restrict__ gw2b,
                         const float* __restrict__ SVH1, bf16* __restrict__ svh1b,
                         const float* __restrict__ SVH2, bf16* __restrict__ svh2b,
                         const float* __restrict__ U1,   bf16* __restrict__ U1T,
                         const float* __restrict__ U2,   bf16* __restrict__ U2T,
                         const float* __restrict__ b1,   const float* __restrict__ TB1,
                         const float* __restrict__ b2,   const float* __restrict__ TB2,
                         float* __restrict__ b1m, float* __restrict__ b2m,
                         float* __restrict__ gsum)
{
    const int b = blockIdx.x;
    const int t = threadIdx.x;
    if      (b < 6144)  cvt_range(x,   xb,   b,         t);
    else if (b < 8448)  cvt_range(W1,  W1b,  b - 6144,  t);
    else if (b < 10752) cvt_range(W2,  W2b,  b - 8448,  t);
    else if (b < 10944) cvt_range(gw1, gw1b, b - 10752, t);
    else if (b < 10976) cvt_range(gw2, gw2b, b - 10944, t);
    else if (b < 11072) cvt_range(SVH1, svh1b, b - 10976, t);
    else if (b < 11456) cvt_range(SVH2, svh2b, b - 11072, t);
    else if (b < 12992) {
        const int i = (b - 11456) * 256 + t;
        if (i < 3072 * 128) {
            const int f = i >> 7, ek = i & 127;
            U1T[i] = __float2bfloat16(U1[ek * 3072 + f]);
        }
        if (i < 768 * 128) {
            const int h = i >> 7, ek = i & 127;
            U2T[i] = __float2bfloat16(U2[ek * 768 + h]);
        }
    } else if (b < 13007) {
        const int i = (b - 12992) * 256 + t;
        if (i < 3072) {
            float s = 0.f;
            for (int e = 0; e < 8; ++e) s += TB1[e * 3072 + i];
            b1m[i] = b1[i] + 0.2f * s;
        } else if (i < 3840) {
            const int j = i - 3072;
            float s = 0.f;
            for (int e = 0; e < 8; ++e) s += TB2[e * 768 + j];
            b2m[j] = b2[j] + 0.2f * s;
        }
    } else {
        const int i = (b - 13007) * 256 + t;   // zero gsum[16*256]
        if (i < 4096) gsum[i] = 0.f;
    }
}

// gw[b,c] = gate_b2[c] + (1/512) * sum_j gsum[b,j] * gate_w2[c,j]
// (mean commutes with the linear g2 layer)
__global__ void gw_kernel(const float* __restrict__ gsum, const bf16* __restrict__ gw2b,
                          const float* __restrict__ gate_b2, float* __restrict__ gw)
{
    const int b = blockIdx.x;
    const int c = threadIdx.x;     // 0..127
    float s = 0.f;
    for (int j = 0; j < 256; ++j)
        s += gsum[b * 256 + j] * __bfloat162float(gw2b[c * 256 + j]);
    gw[b * 128 + c] = gate_b2[c] + s * (1.0f / 512.0f);
}

// ---------------------------------------------------------------------------
extern "C" void kernel_launch(void* const* d_in, const int* in_sizes, int n_in,
                              void* d_out, int out_size, void* d_ws, size_t ws_size,
                              hipStream_t stream)
{
    const float* x       = (const float*)d_in[0];
    const float* gate_w1 = (const float*)d_in[1];
    const float* gate_b1 = (const float*)d_in[2];
    const float* gate_w2 = (const float*)d_in[3];
    const float* gate_b2 = (const float*)d_in[4];
    const float* W1      = (const float*)d_in[5];
    const float* b1      = (const float*)d_in[6];
    const float* W2      = (const float*)d_in[7];
    const float* b2      = (const float*)d_in[8];
    const float* U1      = (const float*)d_in[9];
    const float* SVH1    = (const float*)d_in[10];
    const float* U2      = (const float*)d_in[11];
    const float* SVH2    = (const float*)d_in[12];
    const float* TB1     = (const float*)d_in[13];
    const float* TB2     = (const float*)d_in[14];
    float* out = (float*)d_out;                     // [8192, 768] fp32

    char* p = (char*)d_ws;
    auto alloc = [&](size_t bytes) {
        char* q = p;
        p += (bytes + 255) & ~(size_t)255;
        return q;
    };
    bf16* hbuf  = (bf16*)alloc((size_t)8192 * 3072 * 2);
    bf16* xb    = (bf16*)alloc((size_t)8192 * 768 * 2);
    bf16* t1buf = (bf16*)alloc((size_t)8192 * 128 * 2);
    bf16* t2buf = (bf16*)alloc((size_t)8192 * 128 * 2);
    bf16* W1b   = (bf16*)alloc((size_t)3072 * 768 * 2);
    bf16* W2b   = (bf16*)alloc((size_t)768 * 3072 * 2);
    bf16* gw1b  = (bf16*)alloc((size_t)256 * 768 * 2);
    bf16* gw2b  = (bf16*)alloc((size_t)128 * 256 * 2);
    bf16* svh1b = (bf16*)alloc((size_t)128 * 768 * 2);
    bf16* svh2b = (bf16*)alloc((size_t)128 * 3072 * 2);
    bf16* U1T   = (bf16*)alloc((size_t)3072 * 128 * 2);
    bf16* U2T   = (bf16*)alloc((size_t)768 * 128 * 2);
    float* gsum = (float*)alloc(16 * 256 * 4);
    float* gw   = (float*)alloc(2048 * 4);
    float* b1m  = (float*)alloc(3072 * 4);
    float* b2m  = (float*)alloc(768 * 4);
    float* t2parts = (float*)alloc((size_t)4 * 8192 * 128 * 4);

    const dim3 blk(256);

    prep_all<<<13023, blk, 0, stream>>>(x, xb, W1, W1b, W2, W2b,
                                        gate_w1, gw1b, gate_w2, gw2b,
                                        SVH1, svh1b, SVH2, svh2b,
                                        U1, U1T, U2, U2T,
                                        b1, TB1, b2, TB2, b1m, b2m, gsum);

    // router + fused mean: gsum[b,c] = sum_s relu(x@gw1^T + b1)[b,s,c]
    g1sum_kernel<<<dim3(128, 2), blk, 0, stream>>>(xb, 768, 768, gw1b, 768,
                                                   gate_b1, gsum);
    // gw = gsum/512 @ gate_w2^T + gate_b2              [16, 128]
    gw_kernel<<<16, 128, 0, stream>>>(gsum, gw2b, gate_b2, gw);

    // t1 = (x @ SVH1^T) * gw                           [8192, 128]
    gemm_bt<<<dim3(64, 1), blk, 0, stream>>>(xb, 768, 768, nullptr, 0, 0,
                                             svh1b, 768, nullptr, 0,
                                             nullptr, gw, 0, t1buf, nullptr, 128);
    // h = relu([x|t1] @ [W1|U1T]^T + b1m)              [8192, 3072]
    gemm_bt<<<dim3(64, 24), blk, 0, stream>>>(xb, 768, 768, t1buf, 128, 128,
                                              W1b, 768, U1T, 128,
                                              b1m, nullptr, 1, hbuf, nullptr, 3072);
    // t2 = (h @ SVH2^T) * gw      (split-K=4)          [8192, 128]
    gemm_splitk<<<dim3(64, 1, 4), blk, 0, stream>>>(hbuf, 3072, svh2b, 3072, 12, t2parts);
    combine_kernel<<<4096, blk, 0, stream>>>(t2parts, 4, 8192 * 128, 7, gw, t2buf);
    // out = [h|t2] @ [W2|U2T]^T + b2m  (fp32 out)      [8192, 768]
    gemm_bt64<<<dim3(128, 6), blk, 0, stream>>>(hbuf, 3072, 3072, t2buf, 128, 128,
                                                W2b, 3072, U2T, 128,
                                                b2m, nullptr, 0, nullptr, out, 768);
}

// Round 7
// 306.095 us; speedup vs baseline: 2.8710x; 1.0015x over previous
//
#include <hip/hip_runtime.h>
#include <hip/hip_bf16.h>

using bf16 = __hip_bfloat16;
typedef __bf16 bf16x8 __attribute__((ext_vector_type(8)));
typedef __bf16 bf16x4 __attribute__((ext_vector_type(4)));
typedef float f32x4 __attribute__((ext_vector_type(4)));

#define BM 128
#define BN 128
#define BK 64

// ---------------------------------------------------------------------------
// Staging helper: 16B per lane via global_load_lds, wave-uniform LDS base.
// ---------------------------------------------------------------------------
__device__ __forceinline__ void stage16(const bf16* gsrc, bf16* lds_base)
{
    __builtin_amdgcn_global_load_lds(
        (__attribute__((address_space(1))) void*)(void*)gsrc,
        (__attribute__((address_space(3))) void*)(void*)lds_base,
        16, 0, 0);
}

// LDS chunk swizzle: slot (row, c) holds global chunk (row, c^(row&7)).
// Kills the 16-way ds_read_b128 bank conflict (conflicts 1.65e7 -> 0, R5).

// ---------------------------------------------------------------------------
// 128x128 tiled MFMA GEMM: C = act(A @ B^T + bias), bf16 operands.
// Two K-segments (dense weight | rank-128 delta). fp32 out via Cf, else bf16.
// M%128==0, N%128==0, K0%64==0, K1%64==0. Block=256 (4 waves, 2x2).
// ---------------------------------------------------------------------------
__global__ __launch_bounds__(256)
void gemm_bt(const bf16* __restrict__ A0, int lda0, int K0,
             const bf16* __restrict__ A1, int lda1, int K1,
             const bf16* __restrict__ B0, int ldb0,
             const bf16* __restrict__ B1, int ldb1,
             const float* __restrict__ bias,
             int relu,
             bf16* __restrict__ C, float* __restrict__ Cf, int ldc)
{
    __shared__ bf16 sA[BM * BK];
    __shared__ bf16 sB[BN * BK];

    const int t = threadIdx.x;
    const int w = t >> 6;
    const int l = t & 63;
    const int wm = w >> 1;
    const int wn = w & 1;
    const int r = l & 15;
    const int q = l >> 4;
    const int sw = r & 7;
    const int rowA0 = blockIdx.x * BM;
    const int rowB0 = blockIdx.y * BN;

    f32x4 acc[4][4];
#pragma unroll
    for (int i = 0; i < 4; ++i)
#pragma unroll
        for (int j = 0; j < 4; ++j)
            acc[i][j] = (f32x4){0.f, 0.f, 0.f, 0.f};

    const int nK = (K0 + K1) >> 6;
    for (int kt = 0; kt < nK; ++kt) {
        const int k0 = kt << 6;
        const bf16 *Ap, *Bp;
        int la, lb, ks;
        if (k0 < K0) { Ap = A0; la = lda0; Bp = B0; lb = ldb0; ks = k0; }
        else         { Ap = A1; la = lda1; Bp = B1; lb = ldb1; ks = k0 - K0; }

        __syncthreads();
#pragma unroll
        for (int it = 0; it < 4; ++it) {
            const int L   = it * 256 + t;
            const int row = L >> 3;
            const int cb  = (L & 7) ^ (row & 7);   // swizzled source chunk
            stage16(Ap + (size_t)(rowA0 + row) * la + ks + cb * 8,
                    sA + (size_t)(it * 256 + (w << 6)) * 8);
            stage16(Bp + (size_t)(rowB0 + row) * lb + ks + cb * 8,
                    sB + (size_t)(it * 256 + (w << 6)) * 8);
        }
        __syncthreads();

#pragma unroll
        for (int kk = 0; kk < 2; ++kk) {
            const int ch = ((kk * 4 + q) ^ sw) * 8;
            bf16x8 aF[4], bF[4];
#pragma unroll
            for (int i = 0; i < 4; ++i)
                aF[i] = *(const bf16x8*)&sA[(wm * 64 + i * 16 + r) * BK + ch];
#pragma unroll
            for (int j = 0; j < 4; ++j)
                bF[j] = *(const bf16x8*)&sB[(wn * 64 + j * 16 + r) * BK + ch];
#pragma unroll
            for (int i = 0; i < 4; ++i)
#pragma unroll
                for (int j = 0; j < 4; ++j)
                    acc[i][j] = __builtin_amdgcn_mfma_f32_16x16x32_bf16(
                        aF[i], bF[j], acc[i][j], 0, 0, 0);
        }
    }

    // C/D layout: col = lane&15, row = quad*4 + reg (m89/m91 verified)
#pragma unroll
    for (int i = 0; i < 4; ++i)
#pragma unroll
        for (int j = 0; j < 4; ++j)
#pragma unroll
            for (int rr = 0; rr < 4; ++rr) {
                const int row = rowA0 + wm * 64 + i * 16 + q * 4 + rr;
                const int col = rowB0 + wn * 64 + j * 16 + r;
                float v = acc[i][j][rr];
                if (bias)   v += bias[col];
                if (relu)   v = v > 0.f ? v : 0.f;
                if (Cf) Cf[(size_t)row * ldc + col] = v;
                else    C[(size_t)row * ldc + col] = __float2bfloat16(v);
            }
}

// ---------------------------------------------------------------------------
// 64x128 tile variant (BM=64): doubles block count for N<=768 GEMMs (fc2).
// ---------------------------------------------------------------------------
__global__ __launch_bounds__(256)
void gemm_bt64(const bf16* __restrict__ A0, int lda0, int K0,
               const bf16* __restrict__ A1, int lda1, int K1,
               const bf16* __restrict__ B0, int ldb0,
               const bf16* __restrict__ B1, int ldb1,
               const float* __restrict__ bias,
               int relu,
               bf16* __restrict__ C, float* __restrict__ Cf, int ldc)
{
    __shared__ bf16 sA[64 * BK];
    __shared__ bf16 sB[BN * BK];

    const int t = threadIdx.x;
    const int w = t >> 6;
    const int l = t & 63;
    const int wn = w;
    const int r = l & 15;
    const int q = l >> 4;
    const int sw = r & 7;
    const int rowA0 = blockIdx.x * 64;
    const int rowB0 = blockIdx.y * BN;

    f32x4 acc[4][2];
#pragma unroll
    for (int i = 0; i < 4; ++i)
#pragma unroll
        for (int j = 0; j < 2; ++j)
            acc[i][j] = (f32x4){0.f, 0.f, 0.f, 0.f};

    const int nK = (K0 + K1) >> 6;
    for (int kt = 0; kt < nK; ++kt) {
        const int k0 = kt << 6;
        const bf16 *Ap, *Bp;
        int la, lb, ks;
        if (k0 < K0) { Ap = A0; la = lda0; Bp = B0; lb = ldb0; ks = k0; }
        else         { Ap = A1; la = lda1; Bp = B1; lb = ldb1; ks = k0 - K0; }

        __syncthreads();
#pragma unroll
        for (int it = 0; it < 2; ++it) {
            const int L   = it * 256 + t;
            const int row = L >> 3;
            const int cb  = (L & 7) ^ (row & 7);
            stage16(Ap + (size_t)(rowA0 + row) * la + ks + cb * 8,
                    sA + (size_t)(it * 256 + (w << 6)) * 8);
        }
#pragma unroll
        for (int it = 0; it < 4; ++it) {
            const int L   = it * 256 + t;
            const int row = L >> 3;
            const int cb  = (L & 7) ^ (row & 7);
            stage16(Bp + (size_t)(rowB0 + row) * lb + ks + cb * 8,
                    sB + (size_t)(it * 256 + (w << 6)) * 8);
        }
        __syncthreads();

#pragma unroll
        for (int kk = 0; kk < 2; ++kk) {
            const int ch = ((kk * 4 + q) ^ sw) * 8;
            bf16x8 aF[4], bF[2];
#pragma unroll
            for (int i = 0; i < 4; ++i)
                aF[i] = *(const bf16x8*)&sA[(i * 16 + r) * BK + ch];
#pragma unroll
            for (int j = 0; j < 2; ++j)
                bF[j] = *(const bf16x8*)&sB[(wn * 32 + j * 16 + r) * BK + ch];
#pragma unroll
            for (int i = 0; i < 4; ++i)
#pragma unroll
                for (int j = 0; j < 2; ++j)
                    acc[i][j] = __builtin_amdgcn_mfma_f32_16x16x32_bf16(
                        aF[i], bF[j], acc[i][j], 0, 0, 0);
        }
    }

#pragma unroll
    for (int i = 0; i < 4; ++i)
#pragma unroll
        for (int j = 0; j < 2; ++j)
#pragma unroll
            for (int rr = 0; rr < 4; ++rr) {
                const int row = rowA0 + i * 16 + q * 4 + rr;
                const int col = rowB0 + wn * 32 + j * 16 + r;
                float v = acc[i][j][rr];
                if (bias)   v += bias[col];
                if (relu)   v = v > 0.f ? v : 0.f;
                if (Cf) Cf[(size_t)row * ldc + col] = v;
                else    C[(size_t)row * ldc + col] = __float2bfloat16(v);
            }
}

// ---------------------------------------------------------------------------
// Router GEMM with fused sequence-mean: relu(x@gw1^T+b) summed over rows,
// one fp32 atomicAdd per column into gsum[16,256].
// ---------------------------------------------------------------------------
__global__ __launch_bounds__(256)
void g1sum_kernel(const bf16* __restrict__ A0, int lda0, int K0,
                  const bf16* __restrict__ B0, int ldb0,
                  const float* __restrict__ bias,
                  float* __restrict__ gsum)
{
    __shared__ bf16 sA[64 * BK];
    __shared__ bf16 sB[BN * BK];

    const int t = threadIdx.x;
    const int w = t >> 6;
    const int l = t & 63;
    const int wn = w;
    const int r = l & 15;
    const int q = l >> 4;
    const int sw = r & 7;
    const int rowA0 = blockIdx.x * 64;
    const int rowB0 = blockIdx.y * BN;
    const int b = rowA0 >> 9;

    f32x4 acc[4][2];
#pragma unroll
    for (int i = 0; i < 4; ++i)
#pragma unroll
        for (int j = 0; j < 2; ++j)
            acc[i][j] = (f32x4){0.f, 0.f, 0.f, 0.f};

    const int nK = K0 >> 6;
    for (int kt = 0; kt < nK; ++kt) {
        const int ks = kt << 6;

        __syncthreads();
#pragma unroll
        for (int it = 0; it < 2; ++it) {
            const int L   = it * 256 + t;
            const int row = L >> 3;
            const int cb  = (L & 7) ^ (row & 7);
            stage16(A0 + (size_t)(rowA0 + row) * lda0 + ks + cb * 8,
                    sA + (size_t)(it * 256 + (w << 6)) * 8);
        }
#pragma unroll
        for (int it = 0; it < 4; ++it) {
            const int L   = it * 256 + t;
            const int row = L >> 3;
            const int cb  = (L & 7) ^ (row & 7);
            stage16(B0 + (size_t)(rowB0 + row) * ldb0 + ks + cb * 8,
                    sB + (size_t)(it * 256 + (w << 6)) * 8);
        }
        __syncthreads();

#pragma unroll
        for (int kk = 0; kk < 2; ++kk) {
            const int ch = ((kk * 4 + q) ^ sw) * 8;
            bf16x8 aF[4], bF[2];
#pragma unroll
            for (int i = 0; i < 4; ++i)
                aF[i] = *(const bf16x8*)&sA[(i * 16 + r) * BK + ch];
#pragma unroll
            for (int j = 0; j < 2; ++j)
                bF[j] = *(const bf16x8*)&sB[(wn * 32 + j * 16 + r) * BK + ch];
#pragma unroll
            for (int i = 0; i < 4; ++i)
#pragma unroll
                for (int j = 0; j < 2; ++j)
                    acc[i][j] = __builtin_amdgcn_mfma_f32_16x16x32_bf16(
                        aF[i], bF[j], acc[i][j], 0, 0, 0);
        }
    }

#pragma unroll
    for (int j = 0; j < 2; ++j) {
        const int col = rowB0 + wn * 32 + j * 16 + r;
        const float bc = bias[col];
        float s = 0.f;
#pragma unroll
        for (int i = 0; i < 4; ++i)
#pragma unroll
            for (int rr = 0; rr < 4; ++rr) {
                const float v = acc[i][j][rr] + bc;
                s += v > 0.f ? v : 0.f;
            }
        s += __shfl_xor(s, 16, 64);
        s += __shfl_xor(s, 32, 64);
        if (q == 0) atomicAdd(&gsum[b * 256 + col], s);
    }
}

// ---------------------------------------------------------------------------
// Atomic split-K GEMM for thin-N (N=128): accumulates directly into a
// pre-zeroed fp32 buffer via atomicAdd (no partial buffers, no combine pass).
// grid (M/128, 1, S); each z does ktiles_per 64-wide K-tiles.
// ---------------------------------------------------------------------------
__global__ __launch_bounds__(256)
void gemm_splitk_at(const bf16* __restrict__ A, int lda,
                    const bf16* __restrict__ B, int ldb,
                    int ktiles_per, float* __restrict__ Cacc)
{
    __shared__ bf16 sA[BM * BK];
    __shared__ bf16 sB[BN * BK];

    const int t = threadIdx.x;
    const int w = t >> 6;
    const int l = t & 63;
    const int wm = w >> 1;
    const int wn = w & 1;
    const int r = l & 15;
    const int q = l >> 4;
    const int sw = r & 7;
    const int rowA0 = blockIdx.x * BM;
    const int ksbase = blockIdx.z * ktiles_per * BK;

    f32x4 acc[4][4];
#pragma unroll
    for (int i = 0; i < 4; ++i)
#pragma unroll
        for (int j = 0; j < 4; ++j)
            acc[i][j] = (f32x4){0.f, 0.f, 0.f, 0.f};

    for (int kt = 0; kt < ktiles_per; ++kt) {
        const int ks = ksbase + kt * BK;

        __syncthreads();
#pragma unroll
        for (int it = 0; it < 4; ++it) {
            const int L   = it * 256 + t;
            const int row = L >> 3;
            const int cb  = (L & 7) ^ (row & 7);
            stage16(A + (size_t)(rowA0 + row) * lda + ks + cb * 8,
                    sA + (size_t)(it * 256 + (w << 6)) * 8);
            stage16(B + (size_t)row * ldb + ks + cb * 8,
                    sB + (size_t)(it * 256 + (w << 6)) * 8);
        }
        __syncthreads();

#pragma unroll
        for (int kk = 0; kk < 2; ++kk) {
            const int ch = ((kk * 4 + q) ^ sw) * 8;
            bf16x8 aF[4], bF[4];
#pragma unroll
            for (int i = 0; i < 4; ++i)
                aF[i] = *(const bf16x8*)&sA[(wm * 64 + i * 16 + r) * BK + ch];
#pragma unroll
            for (int j = 0; j < 4; ++j)
                bF[j] = *(const bf16x8*)&sB[(wn * 64 + j * 16 + r) * BK + ch];
#pragma unroll
            for (int i = 0; i < 4; ++i)
#pragma unroll
                for (int j = 0; j < 4; ++j)
                    acc[i][j] = __builtin_amdgcn_mfma_f32_16x16x32_bf16(
                        aF[i], bF[j], acc[i][j], 0, 0, 0);
        }
    }

#pragma unroll
    for (int i = 0; i < 4; ++i)
#pragma unroll
        for (int j = 0; j < 4; ++j)
#pragma unroll
            for (int rr = 0; rr < 4; ++rr) {
                const int row = rowA0 + wm * 64 + i * 16 + q * 4 + rr;
                const int col = wn * 64 + j * 16 + r;
                atomicAdd(&Cacc[(size_t)row * 128 + col], acc[i][j][rr]);
            }
}

// t[i] = bf16(acc[i] * gw[batch(row)][col])   (M x 128)
__global__ void scale_cvt_kernel(const float* __restrict__ acc,
                                 const float* __restrict__ gw,
                                 bf16* __restrict__ outb)
{
    const int i = blockIdx.x * 256 + threadIdx.x;
    const int col = i & 127;
    const int row = i >> 7;
    outb[i] = __float2bfloat16(acc[i] * gw[(row >> 9) * 128 + col]);
}

// ---------------------------------------------------------------------------
// Fused prep: fp32->bf16 casts + coalesced LDS-tile U transposes + merged
// biases + zeroing of gsum / t1acc / t2acc. One launch.
// ---------------------------------------------------------------------------
__device__ __forceinline__ void cvt_range(const float* src, bf16* dst, int base, int t)
{
    const int i = base * 256 + t;
    const float4 v = ((const float4*)src)[i];
    ((bf16x4*)dst)[i] = (bf16x4){(__bf16)v.x, (__bf16)v.y, (__bf16)v.z, (__bf16)v.w};
}

// 64x64 LDS tile transpose: U [128(ek), F] fp32 -> UT [F, 128] bf16
__device__ __forceinline__ void transpose_tile(const float* U, bf16* UT, int F,
                                               int bx, int by, int t,
                                               float (*sh)[65])
{
    const int f0 = bx * 64, ek0 = by * 64;
#pragma unroll
    for (int i = 0; i < 16; ++i) {
        const int row = i * 4 + (t >> 6);      // ek within tile
        const int col = t & 63;                // f within tile
        sh[row][col] = U[(size_t)(ek0 + row) * F + f0 + col];
    }
    __syncthreads();
#pragma unroll
    for (int i = 0; i < 16; ++i) {
        const int row = i * 4 + (t >> 6);      // f within tile
        const int col = t & 63;                // ek within tile
        UT[(size_t)(f0 + row) * 128 + ek0 + col] = __float2bfloat16(sh[col][row]);
    }
}

__global__ void prep_all(const float* __restrict__ x,    bf16* __restrict__ xb,
                         const float* __restrict__ W1,   bf16* __restrict__ W1b,
                         const float* __restrict__ W2,   bf16* __restrict__ W2b,
                         const float* __restrict__ gw1,  bf16* __restrict__ gw1b,
                         const float* __restrict__ gw2,  bf16* __restrict__ gw2b,
                         const float* __restrict__ SVH1, bf16* __restrict__ svh1b,
                         const float* __restrict__ SVH2, bf16* __restrict__ svh2b,
                         const float* __restrict__ U1,   bf16* __restrict__ U1T,
                         const float* __restrict__ U2,   bf16* __restrict__ U2T,
                         const float* __restrict__ b1,   const float* __restrict__ TB1,
                         const float* __restrict__ b2,   const float* __restrict__ TB2,
                         float* __restrict__ b1m, float* __restrict__ b2m,
                         float* __restrict__ gsum, float* __restrict__ acczone)
{
    __shared__ float sh[64][65];
    const int b = blockIdx.x;
    const int t = threadIdx.x;
    if      (b < 6144)  cvt_range(x,   xb,   b,         t);
    else if (b < 8448)  cvt_range(W1,  W1b,  b - 6144,  t);
    else if (b < 10752) cvt_range(W2,  W2b,  b - 8448,  t);
    else if (b < 10944) cvt_range(gw1, gw1b, b - 10752, t);
    else if (b < 10976) cvt_range(gw2, gw2b, b - 10944, t);
    else if (b < 11072) cvt_range(SVH1, svh1b, b - 10976, t);
    else if (b < 11456) cvt_range(SVH2, svh2b, b - 11072, t);
    else if (b < 11552) {          // U1 [128,3072] -> U1T: 48 x 2 tiles
        const int b2 = b - 11456;
        transpose_tile(U1, U1T, 3072, b2 >> 1, b2 & 1, t, sh);
    } else if (b < 11576) {        // U2 [128,768] -> U2T: 12 x 2 tiles
        const int b2 = b - 11552;
        transpose_tile(U2, U2T, 768, b2 >> 1, b2 & 1, t, sh);
    } else if (b < 11591) {        // merged biases
        const int i = (b - 11576) * 256 + t;
        if (i < 3072) {
            float s = 0.f;
            for (int e = 0; e < 8; ++e) s += TB1[e * 3072 + i];
            b1m[i] = b1[i] + 0.2f * s;
        } else if (i < 3840) {
            const int j = i - 3072;
            float s = 0.f;
            for (int e = 0; e < 8; ++e) s += TB2[e * 768 + j];
            b2m[j] = b2[j] + 0.2f * s;
        }
    } else if (b < 11607) {        // zero gsum[4096]
        const int i = (b - 11591) * 256 + t;
        gsum[i] = 0.f;
    } else {                       // zero t1acc+t2acc: 2M floats as float4
        const int i = (b - 11607) * 256 + t;
        ((float4*)acczone)[i] = (float4){0.f, 0.f, 0.f, 0.f};
    }
}

// gw[b,c] = gate_b2[c] + (1/512) * sum_j gsum[b,j] * gate_w2[c,j]
__global__ void gw_kernel(const float* __restrict__ gsum, const bf16* __restrict__ gw2b,
                          const float* __restrict__ gate_b2, float* __restrict__ gw)
{
    const int b = blockIdx.x;
    const int c = threadIdx.x;
    float s = 0.f;
    for (int j = 0; j < 256; ++j)
        s += gsum[b * 256 + j] * __bfloat162float(gw2b[c * 256 + j]);
    gw[b * 128 + c] = gate_b2[c] + s * (1.0f / 512.0f);
}

// ---------------------------------------------------------------------------
extern "C" void kernel_launch(void* const* d_in, const int* in_sizes, int n_in,
                              void* d_out, int out_size, void* d_ws, size_t ws_size,
                              hipStream_t stream)
{
    const float* x       = (const float*)d_in[0];
    const float* gate_w1 = (const float*)d_in[1];
    const float* gate_b1 = (const float*)d_in[2];
    const float* gate_w2 = (const float*)d_in[3];
    const float* gate_b2 = (const float*)d_in[4];
    const float* W1      = (const float*)d_in[5];
    const float* b1      = (const float*)d_in[6];
    const float* W2      = (const float*)d_in[7];
    const float* b2      = (const float*)d_in[8];
    const float* U1      = (const float*)d_in[9];
    const float* SVH1    = (const float*)d_in[10];
    const float* U2      = (const float*)d_in[11];
    const float* SVH2    = (const float*)d_in[12];
    const float* TB1     = (const float*)d_in[13];
    const float* TB2     = (const float*)d_in[14];
    float* out = (float*)d_out;                     // [8192, 768] fp32

    char* p = (char*)d_ws;
    auto alloc = [&](size_t bytes) {
        char* q = p;
        p += (bytes + 255) & ~(size_t)255;
        return q;
    };
    bf16* hbuf  = (bf16*)alloc((size_t)8192 * 3072 * 2);
    bf16* xb    = (bf16*)alloc((size_t)8192 * 768 * 2);
    bf16* t1buf = (bf16*)alloc((size_t)8192 * 128 * 2);
    bf16* t2buf = (bf16*)alloc((size_t)8192 * 128 * 2);
    bf16* W1b   = (bf16*)alloc((size_t)3072 * 768 * 2);
    bf16* W2b   = (bf16*)alloc((size_t)768 * 3072 * 2);
    bf16* gw1b  = (bf16*)alloc((size_t)256 * 768 * 2);
    bf16* gw2b  = (bf16*)alloc((size_t)128 * 256 * 2);
    bf16* svh1b = (bf16*)alloc((size_t)128 * 768 * 2);
    bf16* svh2b = (bf16*)alloc((size_t)128 * 3072 * 2);
    bf16* U1T   = (bf16*)alloc((size_t)3072 * 128 * 2);
    bf16* U2T   = (bf16*)alloc((size_t)768 * 128 * 2);
    float* gsum = (float*)alloc(16 * 256 * 4);
    float* gw   = (float*)alloc(2048 * 4);
    float* b1m  = (float*)alloc(3072 * 4);
    float* b2m  = (float*)alloc(768 * 4);
    float* acczone = (float*)alloc((size_t)2 * 8192 * 128 * 4);  // t1acc|t2acc
    float* t1acc = acczone;
    float* t2acc = acczone + (size_t)8192 * 128;

    const dim3 blk(256);

    prep_all<<<13655, blk, 0, stream>>>(x, xb, W1, W1b, W2, W2b,
                                        gate_w1, gw1b, gate_w2, gw2b,
                                        SVH1, svh1b, SVH2, svh2b,
                                        U1, U1T, U2, U2T,
                                        b1, TB1, b2, TB2, b1m, b2m,
                                        gsum, acczone);

    // router + fused mean: gsum[b,c] = sum_s relu(x@gw1^T + b1)[b,s,c]
    g1sum_kernel<<<dim3(128, 2), blk, 0, stream>>>(xb, 768, 768, gw1b, 768,
                                                   gate_b1, gsum);
    // gw = gsum/512 @ gate_w2^T + gate_b2              [16, 128]
    gw_kernel<<<16, 128, 0, stream>>>(gsum, gw2b, gate_b2, gw);

    // t1raw = x @ SVH1^T  (atomic split-K=4), then t1 = t1raw * gw
    gemm_splitk_at<<<dim3(64, 1, 4), blk, 0, stream>>>(xb, 768, svh1b, 768, 3, t1acc);
    scale_cvt_kernel<<<4096, blk, 0, stream>>>(t1acc, gw, t1buf);

    // h = relu([x|t1] @ [W1|U1T]^T + b1m)              [8192, 3072]
    gemm_bt<<<dim3(64, 24), blk, 0, stream>>>(xb, 768, 768, t1buf, 128, 128,
                                              W1b, 768, U1T, 128,
                                              b1m, 1, hbuf, nullptr, 3072);

    // t2raw = h @ SVH2^T  (atomic split-K=4), then t2 = t2raw * gw
    gemm_splitk_at<<<dim3(64, 1, 4), blk, 0, stream>>>(hbuf, 3072, svh2b, 3072, 12, t2acc);
    scale_cvt_kernel<<<4096, blk, 0, stream>>>(t2acc, gw, t2buf);

    // out = [h|t2] @ [W2|U2T]^T + b2m  (fp32 out)      [8192, 768]
    gemm_bt64<<<dim3(128, 6), blk, 0, stream>>>(hbuf, 3072, 3072, t2buf, 128, 128,
                                                W2b, 3072, U2T, 128,
                                                b2m, 0, nullptr, out, 768);
}